// Round 1
// baseline (531.094 us; speedup 1.0000x reference)
//
#include <hip/hip_runtime.h>
#include <hip/hip_bf16.h>
#include <cstdint>
#include <cstddef>

typedef __bf16 bf16;
typedef __attribute__((ext_vector_type(8))) __bf16 bf16x8;
typedef __attribute__((ext_vector_type(4))) float f32x4;
typedef __attribute__((ext_vector_type(4))) float floatx4;

// Problem constants
#define NTOK 8192
#define DIMM 1152
#define NH   16
#define HD   72
#define HDP  96      // padded head dim (3 x 32 for MFMA K)
#define SEGS 4
#define SEGL 2048

__device__ __forceinline__ void gload16(const void* gsrc, void* ldst) {
  __builtin_amdgcn_global_load_lds(
      (const __attribute__((address_space(1))) void*)gsrc,
      (__attribute__((address_space(3))) void*)ldst,
      16, 0, 0);
}

// ---------------- f32 -> bf16 elementwise convert (8 elems/thread) -------------
__global__ __launch_bounds__(256) void k_cvt(const float* __restrict__ src,
                                             bf16* __restrict__ dst, int n8) {
  int i = blockIdx.x * 256 + threadIdx.x;
  if (i >= n8) return;
  const floatx4* s = (const floatx4*)src + (size_t)i * 2;
  floatx4 a = s[0], b = s[1];
  bf16x8 o;
  o[0] = (bf16)a.x; o[1] = (bf16)a.y; o[2] = (bf16)a.z; o[3] = (bf16)a.w;
  o[4] = (bf16)b.x; o[5] = (bf16)b.y; o[6] = (bf16)b.z; o[7] = (bf16)b.w;
  *((bf16x8*)dst + i) = o;
}

// ---------------- transpose + convert: src[R][C] f32 -> dst[C][R] bf16 ---------
__global__ __launch_bounds__(256) void k_twt(const float* __restrict__ src,
                                             bf16* __restrict__ dst, int R, int C) {
  __shared__ bf16 tile[64][73];
  int bc = blockIdx.x * 64, br = blockIdx.y * 64;
  int t = threadIdx.x;
#pragma unroll
  for (int i = 0; i < 16; i++) {
    int idx = i * 256 + t;
    int r = idx >> 6, c = idx & 63;
    tile[c][r] = (bf16)src[(size_t)(br + r) * C + bc + c];
  }
  __syncthreads();
#pragma unroll
  for (int i = 0; i < 16; i++) {
    int idx = i * 256 + t;
    int r = idx >> 6, c = idx & 63;
    dst[(size_t)(bc + r) * R + br + c] = tile[r][c];
  }
}

// ---------------- bf16 GEMM: C[M][N] = A[M][K] * Bt[N][K]^T + bias -------------
// 128x128 tile, BK=64, 4 waves each computing 64x64 (4x4 16x16x32 MFMA frags)
template <bool OUT_F32>
__global__ __launch_bounds__(256) void k_gemm(const bf16* __restrict__ A,
                                              const bf16* __restrict__ Bt,
                                              const float* __restrict__ bias,
                                              void* __restrict__ Cout,
                                              int M, int N, int K) {
  __shared__ bf16 sA[128 * 64];
  __shared__ bf16 sB[128 * 64];
  const int t = threadIdx.x, wave = t >> 6, lane = t & 63;
  const int lr = lane & 15, lg = lane >> 4;
  const int m0 = blockIdx.y * 128, n0 = blockIdx.x * 128;
  const int wm = (wave >> 1) * 64, wn = (wave & 1) * 64;
  f32x4 acc[4][4];
#pragma unroll
  for (int i = 0; i < 4; i++)
#pragma unroll
    for (int j = 0; j < 4; j++)
#pragma unroll
      for (int q = 0; q < 4; q++) acc[i][j][q] = 0.f;

  const bf16* Ab = A + (size_t)m0 * K;
  const bf16* Bb = Bt + (size_t)n0 * K;

  for (int k0 = 0; k0 < K; k0 += 64) {
#pragma unroll
    for (int it = 0; it < 4; ++it) {
      int e = it * 2048 + t * 8;       // element index in [128][64] tile
      int r = e >> 6, c = e & 63;
      gload16(Ab + (size_t)r * K + (k0 + c), (char*)sA + it * 4096 + wave * 1024);
      gload16(Bb + (size_t)r * K + (k0 + c), (char*)sB + it * 4096 + wave * 1024);
    }
    __syncthreads();
#pragma unroll
    for (int kk = 0; kk < 2; ++kk) {
      bf16x8 av[4], bv[4];
#pragma unroll
      for (int mi = 0; mi < 4; ++mi)
        av[mi] = *(const bf16x8*)&sA[(wm + mi * 16 + lr) * 64 + kk * 32 + lg * 8];
#pragma unroll
      for (int ni = 0; ni < 4; ++ni)
        bv[ni] = *(const bf16x8*)&sB[(wn + ni * 16 + lr) * 64 + kk * 32 + lg * 8];
#pragma unroll
      for (int mi = 0; mi < 4; ++mi)
#pragma unroll
        for (int ni = 0; ni < 4; ++ni)
          acc[mi][ni] = __builtin_amdgcn_mfma_f32_16x16x32_bf16(av[mi], bv[ni], acc[mi][ni], 0, 0, 0);
    }
    __syncthreads();
  }
  // epilogue: C/D layout col = lane&15, row = (lane>>4)*4 + reg
#pragma unroll
  for (int mi = 0; mi < 4; ++mi)
#pragma unroll
    for (int ni = 0; ni < 4; ++ni) {
      int col = n0 + wn + ni * 16 + lr;
      float bc_ = bias[col];
#pragma unroll
      for (int j = 0; j < 4; j++) {
        int row = m0 + wm + mi * 16 + lg * 4 + j;
        float v = acc[mi][ni][j] + bc_;
        if (OUT_F32)
          ((float*)Cout)[(size_t)row * N + col] = v;
        else
          ((bf16*)Cout)[(size_t)row * N + col] = (bf16)v;
      }
    }
}

// ---------------- RoPE + repack Q,K: qkv[n][3456] -> Qp/Kp[s][h][l][96] --------
__global__ __launch_bounds__(256) void k_rope(const bf16* __restrict__ qkv,
                                              const float* __restrict__ cs,
                                              const float* __restrict__ sn,
                                              bf16* __restrict__ Qp,
                                              bf16* __restrict__ Kp) {
  int n = blockIdx.x;
  int s = n >> 11, l = n & 2047;
  const bf16* row = qkv + (size_t)n * (3 * DIMM);
  const float* cr = cs + (size_t)n * HD;
  const float* sr = sn + (size_t)n * HD;
  for (int e = threadIdx.x; e < 2 * NH * HDP; e += 256) {
    int which = e / (NH * HDP);          // 0=q, 1=k
    int r = e - which * (NH * HDP);
    int h = r / HDP;
    int d = r - h * HDP;
    float v = 0.f;
    if (d < HD) {
      int base = which * DIMM + h * HD;
      float x = (float)row[base + d];
      float other = (d < 36) ? -(float)row[base + d + 36] : (float)row[base + d - 36];
      v = x * cr[d] + other * sr[d];
    }
    bf16* dst = which ? Kp : Qp;
    dst[(((size_t)s * NH + h) * SEGL + l) * HDP + d] = (bf16)v;
  }
}

// ---------------- V repack (transpose): qkv v-part -> Vt[s][h][96][2048] -------
__global__ __launch_bounds__(256) void k_vrep(const bf16* __restrict__ qkv,
                                              bf16* __restrict__ Vt) {
  int s = blockIdx.z, h = blockIdx.y, l0 = blockIdx.x * 64;
  __shared__ bf16 tl[64][73];
  int t = threadIdx.x;
  for (int idx = t; idx < 64 * HD; idx += 256) {
    int l = idx / HD, d = idx - l * HD;
    tl[l][d] = qkv[(size_t)(s * SEGL + l0 + l) * (3 * DIMM) + 2 * DIMM + h * HD + d];
  }
  __syncthreads();
  for (int idx = t; idx < HDP * 64; idx += 256) {
    int d = idx >> 6, l = idx & 63;
    bf16 v = (d < HD) ? tl[l][d] : (bf16)0.f;
    Vt[((size_t)(s * NH + h) * HDP + d) * SEGL + l0 + l] = v;
  }
}

// ---------------- flash attention: per (seg, head, 128-row q tile) -------------
__global__ __launch_bounds__(256) void k_attn(const bf16* __restrict__ Qp,
                                              const bf16* __restrict__ Kp,
                                              const bf16* __restrict__ Vt,
                                              bf16* __restrict__ Oo) {
  __shared__ bf16 sQ[128 * HDP];    // 24 KB
  __shared__ bf16 sK[64 * HDP];     // 12 KB
  __shared__ bf16 sV[HDP * 64];     // 12 KB  (Vt tile: [d][kv])
  __shared__ bf16 sP[4][32 * 64];   // 16 KB  (per-wave P buffer)
  const int s = blockIdx.z, h = blockIdx.y, q0 = blockIdx.x * 128;
  const int t = threadIdx.x, wave = t >> 6, lane = t & 63;
  const int lr = lane & 15, lg = lane >> 4;
  const bf16* Qb = Qp + ((size_t)(s * NH + h) * SEGL + q0) * HDP;
  const bf16* Kb = Kp + (size_t)(s * NH + h) * SEGL * HDP;
  const bf16* Vb = Vt + (size_t)(s * NH + h) * HDP * SEGL;

  // stage Q once: 24 KB = 24 chunks of 1KB (linear copy)
#pragma unroll
  for (int i = 0; i < 6; i++) {
    int ch = wave * 6 + i;
    gload16(Qb + ch * 512 + lane * 8, (char*)sQ + ch * 1024);
  }

  f32x4 accO[2][5];
#pragma unroll
  for (int i = 0; i < 2; i++)
#pragma unroll
    for (int j = 0; j < 5; j++)
#pragma unroll
      for (int q = 0; q < 4; q++) accO[i][j][q] = 0.f;
  float mrow[2][4], lrow[2][4];
#pragma unroll
  for (int i = 0; i < 2; i++)
#pragma unroll
    for (int j = 0; j < 4; j++) { mrow[i][j] = -3.0e38f; lrow[i][j] = 0.f; }

  const float scale = 0.1178511301977579f;  // 1/sqrt(72)

  for (int kv0 = 0; kv0 < SEGL; kv0 += 64) {
    // stage K tile [64][96] (linear) and V tile [96][64] (row segments)
#pragma unroll
    for (int i = 0; i < 3; i++) {
      int ch = wave * 3 + i;
      gload16(Kb + (size_t)kv0 * HDP + ch * 512 + lane * 8, (char*)sK + ch * 1024);
    }
#pragma unroll
    for (int i = 0; i < 3; i++) {
      int ch = wave * 3 + i;
      int vrow = ch * 8 + (lane >> 3);
      gload16(Vb + (size_t)vrow * SEGL + kv0 + (lane & 7) * 8, (char*)sV + ch * 1024);
    }
    __syncthreads();

    // S = Q K^T  (contraction over padded d = 96)
    f32x4 sc[2][4];
#pragma unroll
    for (int i = 0; i < 2; i++)
#pragma unroll
      for (int j = 0; j < 4; j++)
#pragma unroll
        for (int q = 0; q < 4; q++) sc[i][j][q] = 0.f;
#pragma unroll
    for (int kk = 0; kk < 3; kk++) {
      bf16x8 aq[2], bk[4];
#pragma unroll
      for (int mi = 0; mi < 2; mi++)
        aq[mi] = *(const bf16x8*)&sQ[(wave * 32 + mi * 16 + lr) * HDP + kk * 32 + lg * 8];
#pragma unroll
      for (int ni = 0; ni < 4; ni++)
        bk[ni] = *(const bf16x8*)&sK[(ni * 16 + lr) * HDP + kk * 32 + lg * 8];
#pragma unroll
      for (int mi = 0; mi < 2; mi++)
#pragma unroll
        for (int ni = 0; ni < 4; ni++)
          sc[mi][ni] = __builtin_amdgcn_mfma_f32_16x16x32_bf16(aq[mi], bk[ni], sc[mi][ni], 0, 0, 0);
    }

    // online softmax; rows owned per lane: (mi, lg*4+j); cols across 16 lanes x 4 ni
#pragma unroll
    for (int mi = 0; mi < 2; mi++)
#pragma unroll
      for (int j = 0; j < 4; j++) {
        float s0 = fmaxf(fmaxf(sc[mi][0][j], sc[mi][1][j]),
                         fmaxf(sc[mi][2][j], sc[mi][3][j])) * scale;
#pragma unroll
        for (int off = 1; off < 16; off <<= 1) s0 = fmaxf(s0, __shfl_xor(s0, off, 64));
        float mold = mrow[mi][j];
        float mnew = fmaxf(mold, s0);
        float al = __expf(mold - mnew);
        mrow[mi][j] = mnew;
        float rs = 0.f;
#pragma unroll
        for (int ni = 0; ni < 4; ni++) {
          float p = __expf(sc[mi][ni][j] * scale - mnew);
          rs += p;
          sP[wave][(mi * 16 + lg * 4 + j) * 64 + ni * 16 + lr] = (bf16)p;
        }
#pragma unroll
        for (int off = 1; off < 16; off <<= 1) rs += __shfl_xor(rs, off, 64);
        lrow[mi][j] = lrow[mi][j] * al + rs;
#pragma unroll
        for (int ni = 0; ni < 5; ni++) accO[mi][ni][j] *= al;
      }
    asm volatile("s_waitcnt lgkmcnt(0)" ::: "memory");

    // O += P V   (A = P from LDS in A-layout, B = Vt tile)
#pragma unroll
    for (int kk = 0; kk < 2; kk++) {
      bf16x8 ap[2], bvv[5];
#pragma unroll
      for (int mi = 0; mi < 2; mi++)
        ap[mi] = *(const bf16x8*)&sP[wave][(mi * 16 + lr) * 64 + kk * 32 + lg * 8];
#pragma unroll
      for (int ni = 0; ni < 5; ni++)
        bvv[ni] = *(const bf16x8*)&sV[(ni * 16 + lr) * 64 + kk * 32 + lg * 8];
#pragma unroll
      for (int mi = 0; mi < 2; mi++)
#pragma unroll
        for (int ni = 0; ni < 5; ni++)
          accO[mi][ni] = __builtin_amdgcn_mfma_f32_16x16x32_bf16(ap[mi], bvv[ni], accO[mi][ni], 0, 0, 0);
    }
    __syncthreads();
  }

  // write attn output (token-major [n][h*72+d]) for d < 72
#pragma unroll
  for (int mi = 0; mi < 2; mi++)
#pragma unroll
    for (int ni = 0; ni < 5; ni++)
#pragma unroll
      for (int j = 0; j < 4; j++) {
        int col = ni * 16 + lr;
        if (col < HD) {
          int n = s * SEGL + q0 + wave * 32 + mi * 16 + lg * 4 + j;
          float v = accO[mi][ni][j] / lrow[mi][j];
          Oo[(size_t)n * DIMM + h * HD + col] = (bf16)v;
        }
      }
}

// -------------------------------------------------------------------------------
extern "C" void kernel_launch(void* const* d_in, const int* in_sizes, int n_in,
                              void* d_out, int out_size, void* d_ws, size_t ws_size,
                              hipStream_t stream) {
  (void)in_sizes; (void)n_in; (void)out_size; (void)ws_size;
  const float* hs     = (const float*)d_in[0];
  const float* cosp   = (const float*)d_in[1];
  const float* sinp   = (const float*)d_in[2];
  /* d_in[3] = cu_seqlens (uniform segments, compile-time constant here) */
  const float* w_qkv  = (const float*)d_in[4];
  const float* b_qkv  = (const float*)d_in[5];
  const float* w_proj = (const float*)d_in[6];
  const float* b_proj = (const float*)d_in[7];
  float* out = (float*)d_out;

  char* ws = (char*)d_ws;
  bf16* hsb    = (bf16*)(ws + 0);          // 8192*1152*2        = 18874368
  bf16* wqkvT  = (bf16*)(ws + 18874368);   // 3456*1152*2        =  7962624
  bf16* wprojT = (bf16*)(ws + 26836992);   // 1152*1152*2        =  2654208
  bf16* qkv    = (bf16*)(ws + 29491200);   // 8192*3456*2        = 56623104
  bf16* Qp     = (bf16*)(ws + 86114304);   // 4*16*2048*96*2     = 25165824
  bf16* Kp     = (bf16*)(ws + 111280128);  // 25165824
  bf16* Vt     = (bf16*)(ws + 136445952);  // 25165824
  bf16* ao     = (bf16*)(ws + 161611776);  // 8192*1152*2        = 18874368
  // total = 180486144 bytes

  k_cvt<<<4608, 256, 0, stream>>>(hs, hsb, 1179648);                       // 8192*1152/8
  k_twt<<<dim3(54, 18), 256, 0, stream>>>(w_qkv, wqkvT, 1152, 3456);
  k_twt<<<dim3(18, 18), 256, 0, stream>>>(w_proj, wprojT, 1152, 1152);
  k_gemm<false><<<dim3(27, 64), 256, 0, stream>>>(hsb, wqkvT, b_qkv, (void*)qkv, 8192, 3456, 1152);
  k_rope<<<8192, 256, 0, stream>>>(qkv, cosp, sinp, Qp, Kp);
  k_vrep<<<dim3(32, 16, 4), 256, 0, stream>>>(qkv, Vt);
  k_attn<<<dim3(16, 16, 4), 256, 0, stream>>>(Qp, Kp, Vt, ao);
  k_gemm<true><<<dim3(9, 64), 256, 0, stream>>>(ao, wprojT, b_proj, (void*)out, 8192, 1152, 1152);
}

// Round 2
// 401.128 us; speedup vs baseline: 1.3240x; 1.3240x over previous
//
#include <hip/hip_runtime.h>
#include <hip/hip_bf16.h>
#include <cstdint>
#include <cstddef>

typedef __bf16 bf16;
typedef __attribute__((ext_vector_type(8))) __bf16 bf16x8;
typedef __attribute__((ext_vector_type(4))) float f32x4;
typedef __attribute__((ext_vector_type(16))) float f32x16;
typedef __attribute__((ext_vector_type(4))) float floatx4;
typedef __attribute__((ext_vector_type(4))) unsigned short ushort4_t;

// Problem constants
#define NTOK 8192
#define DIMM 1152
#define NH   16
#define HD   72
#define SEGS 4
#define SEGL 2048

__device__ __forceinline__ void gload16(const void* gsrc, void* ldst) {
  __builtin_amdgcn_global_load_lds(
      (const __attribute__((address_space(1))) void*)gsrc,
      (__attribute__((address_space(3))) void*)ldst,
      16, 0, 0);
}

__device__ __forceinline__ unsigned pk2(float a, float b) {
  unsigned short x = __builtin_bit_cast(unsigned short, (bf16)a);
  unsigned short y = __builtin_bit_cast(unsigned short, (bf16)b);
  return (unsigned)x | ((unsigned)y << 16);
}

// ---------------- f32 -> bf16 elementwise convert (8 elems/thread) -------------
__global__ __launch_bounds__(256) void k_cvt(const float* __restrict__ src,
                                             bf16* __restrict__ dst, int n8) {
  int i = blockIdx.x * 256 + threadIdx.x;
  if (i >= n8) return;
  const floatx4* s = (const floatx4*)src + (size_t)i * 2;
  floatx4 a = s[0], b = s[1];
  bf16x8 o;
  o[0] = (bf16)a.x; o[1] = (bf16)a.y; o[2] = (bf16)a.z; o[3] = (bf16)a.w;
  o[4] = (bf16)b.x; o[5] = (bf16)b.y; o[6] = (bf16)b.z; o[7] = (bf16)b.w;
  *((bf16x8*)dst + i) = o;
}

// ---------------- transpose + convert: src[R][C] f32 -> dst[C][R] bf16 ---------
__global__ __launch_bounds__(256) void k_twt(const float* __restrict__ src,
                                             bf16* __restrict__ dst, int R, int C) {
  __shared__ bf16 tile[64][73];
  int bc = blockIdx.x * 64, br = blockIdx.y * 64;
  int t = threadIdx.x;
#pragma unroll
  for (int i = 0; i < 16; i++) {
    int idx = i * 256 + t;
    int r = idx >> 6, c = idx & 63;
    tile[c][r] = (bf16)src[(size_t)(br + r) * C + bc + c];
  }
  __syncthreads();
#pragma unroll
  for (int i = 0; i < 16; i++) {
    int idx = i * 256 + t;
    int r = idx >> 6, c = idx & 63;
    dst[(size_t)(bc + r) * R + br + c] = tile[r][c];
  }
}

// ---------------- bf16 GEMM: C[M][N] = A[M][K] * Bt[N][K]^T + bias -------------
template <bool OUT_F32>
__global__ __launch_bounds__(256) void k_gemm(const bf16* __restrict__ A,
                                              const bf16* __restrict__ Bt,
                                              const float* __restrict__ bias,
                                              void* __restrict__ Cout,
                                              int M, int N, int K) {
  __shared__ bf16 sA[128 * 64];
  __shared__ bf16 sB[128 * 64];
  const int t = threadIdx.x, wave = t >> 6, lane = t & 63;
  const int lr = lane & 15, lg = lane >> 4;
  const int m0 = blockIdx.y * 128, n0 = blockIdx.x * 128;
  const int wm = (wave >> 1) * 64, wn = (wave & 1) * 64;
  f32x4 acc[4][4];
#pragma unroll
  for (int i = 0; i < 4; i++)
#pragma unroll
    for (int j = 0; j < 4; j++)
#pragma unroll
      for (int q = 0; q < 4; q++) acc[i][j][q] = 0.f;

  const bf16* Ab = A + (size_t)m0 * K;
  const bf16* Bb = Bt + (size_t)n0 * K;

  for (int k0 = 0; k0 < K; k0 += 64) {
#pragma unroll
    for (int it = 0; it < 4; ++it) {
      int e = it * 2048 + t * 8;
      int r = e >> 6, c = e & 63;
      gload16(Ab + (size_t)r * K + (k0 + c), (char*)sA + it * 4096 + wave * 1024);
      gload16(Bb + (size_t)r * K + (k0 + c), (char*)sB + it * 4096 + wave * 1024);
    }
    __syncthreads();
#pragma unroll
    for (int kk = 0; kk < 2; ++kk) {
      bf16x8 av[4], bv[4];
#pragma unroll
      for (int mi = 0; mi < 4; ++mi)
        av[mi] = *(const bf16x8*)&sA[(wm + mi * 16 + lr) * 64 + kk * 32 + lg * 8];
#pragma unroll
      for (int ni = 0; ni < 4; ++ni)
        bv[ni] = *(const bf16x8*)&sB[(wn + ni * 16 + lr) * 64 + kk * 32 + lg * 8];
#pragma unroll
      for (int mi = 0; mi < 4; ++mi)
#pragma unroll
        for (int ni = 0; ni < 4; ++ni)
          acc[mi][ni] = __builtin_amdgcn_mfma_f32_16x16x32_bf16(av[mi], bv[ni], acc[mi][ni], 0, 0, 0);
    }
    __syncthreads();
  }
#pragma unroll
  for (int mi = 0; mi < 4; ++mi)
#pragma unroll
    for (int ni = 0; ni < 4; ++ni) {
      int col = n0 + wn + ni * 16 + lr;
      float bc_ = bias[col];
#pragma unroll
      for (int j = 0; j < 4; j++) {
        int row = m0 + wm + mi * 16 + lg * 4 + j;
        float v = acc[mi][ni][j] + bc_;
        if (OUT_F32)
          ((float*)Cout)[(size_t)row * N + col] = v;
        else
          ((bf16*)Cout)[(size_t)row * N + col] = (bf16)v;
      }
    }
}

// ---------------- RoPE + repack Q,K: qkv[n][3456] -> Qp/Kp[s][h][3][2048][32] --
// Q is pre-scaled by log2(e)/sqrt(72) so attention works in exp2 domain.
__global__ __launch_bounds__(256) void k_rope(const bf16* __restrict__ qkv,
                                              const float* __restrict__ cs,
                                              const float* __restrict__ sn,
                                              bf16* __restrict__ Qp,
                                              bf16* __restrict__ Kp) {
  int n = blockIdx.x;
  int s = n >> 11, l = n & 2047;
  const bf16* row = qkv + (size_t)n * (3 * DIMM);
  const float* cr = cs + (size_t)n * HD;
  const float* sr = sn + (size_t)n * HD;
  const float QS = 0.17002323f;  // log2(e)/sqrt(72)
  for (int e = threadIdx.x; e < 3072; e += 256) {
    int which = e / 1536;             // 0=q, 1=k
    int r = e - which * 1536;
    int h = r / 96;
    int d = r - h * 96;
    float v = 0.f;
    if (d < HD) {
      int base = which * DIMM + h * HD;
      float x = (float)row[base + d];
      float o = (d < 36) ? -(float)row[base + d + 36] : (float)row[base + d - 36];
      v = x * cr[d] + o * sr[d];
      if (which == 0) v *= QS;
    }
    bf16* dst = which ? Kp : Qp;
    dst[(((size_t)(s * NH + h) * 3 + (d >> 5)) * SEGL + l) * 32 + (d & 31)] = (bf16)v;
  }
}

// ---------------- V repack (transpose): qkv v-part -> Vt[s][h][96][2048] -------
__global__ __launch_bounds__(256) void k_vrep(const bf16* __restrict__ qkv,
                                              bf16* __restrict__ Vt) {
  int s = blockIdx.z, h = blockIdx.y, l0 = blockIdx.x * 64;
  __shared__ bf16 tl[64][73];
  int t = threadIdx.x;
  for (int idx = t; idx < 64 * HD; idx += 256) {
    int l = idx / HD, d = idx - l * HD;
    tl[l][d] = qkv[(size_t)(s * SEGL + l0 + l) * (3 * DIMM) + 2 * DIMM + h * HD + d];
  }
  __syncthreads();
  for (int idx = t; idx < 96 * 64; idx += 256) {
    int d = idx >> 6, l = idx & 63;
    bf16 v = (d < HD) ? tl[l][d] : (bf16)0.f;
    Vt[((size_t)(s * NH + h) * 96 + d) * SEGL + l0 + l] = v;
  }
}

// ---------------- flash attention, swapped-operand 32x32 MFMA ------------------
// Block: 4 waves x 64 q-rows = 256-q tile. Wave computes S^T = K·Q (lane owns one
// q column per sni), in-register softmax (exp2 domain), in-register P^T build,
// O^T = V^T · P^T. LDS: sQ[3][256][32], sK[3][64][32], sV[96][64], XOR-swizzled
// granules via pre-swizzled global_load_lds sources.
__global__ __launch_bounds__(256, 2) void k_attn(const bf16* __restrict__ Qg,
                                                 const bf16* __restrict__ Kg,
                                                 const bf16* __restrict__ Vg,
                                                 bf16* __restrict__ Oo) {
  __shared__ bf16 sQ[3 * 256 * 32];   // 48 KB
  __shared__ bf16 sK[3 * 64 * 32];    // 12 KB
  __shared__ bf16 sV[96 * 64];        // 12 KB
  const int t = threadIdx.x, wave = t >> 6, lane = t & 63;
  const int c = lane & 31, hi = lane >> 5;
  const int s = blockIdx.z, h = blockIdx.y, q0 = blockIdx.x * 256;
  const bf16* Qb = Qg + (size_t)(s * NH + h) * 3 * SEGL * 32;
  const bf16* Kb = Kg + (size_t)(s * NH + h) * 3 * SEGL * 32;
  const bf16* Vb = Vg + (size_t)(s * NH + h) * 96 * SEGL;

  // ---- stage Q (48 chunks of 1 KB, per-lane swizzled source) ----
#pragma unroll
  for (int i = 0; i < 12; i++) {
    int ch = wave * 12 + i;           // 0..47 ; 16 chunks per kk plane
    int kk = ch >> 4;
    int r = (ch & 15) * 16 + (lane >> 2);
    int g = (lane & 3) ^ ((r >> 1) & 3);
    gload16(Qb + (size_t)kk * (SEGL * 32) + (size_t)(q0 + r) * 32 + g * 8,
            (char*)sQ + ch * 1024);
  }
  // ---- stage K,V tile 0 ----
  {
    int kv0 = 0;
#pragma unroll
    for (int i = 0; i < 3; i++) {
      int ch = wave * 3 + i;          // 0..11 ; 4 chunks per kk plane
      int kk = ch >> 2;
      int r = (ch & 3) * 16 + (lane >> 2);
      int g = (lane & 3) ^ ((r >> 1) & 3);
      gload16(Kb + (size_t)kk * (SEGL * 32) + (size_t)(kv0 + r) * 32 + g * 8,
              (char*)sK + ch * 1024);
    }
#pragma unroll
    for (int i = 0; i < 3; i++) {
      int ch = wave * 3 + i;          // 0..11 ; 8 V-rows per chunk
      int r = ch * 8 + (lane >> 3);
      int g = (lane & 7) ^ (r & 7);
      gload16(Vb + (size_t)r * SEGL + kv0 + g * 8, (char*)sV + ch * 1024);
    }
  }
  __syncthreads();

  // ---- hoist Q fragments (constant across kv tiles) ----
  bf16x8 Qf[2][5];
#pragma unroll
  for (int sni = 0; sni < 2; sni++)
#pragma unroll
    for (int kk = 0; kk < 5; kk++) {
      int qr = wave * 64 + sni * 32 + c;
      int g = (((kk & 1) * 2 + hi) ^ ((qr >> 1) & 3));
      Qf[sni][kk] = *(const bf16x8*)&sQ[(kk >> 1) * 8192 + qr * 32 + g * 8];
    }

  f32x16 accO[3][2];
#pragma unroll
  for (int df = 0; df < 3; df++)
#pragma unroll
    for (int sni = 0; sni < 2; sni++)
#pragma unroll
      for (int r = 0; r < 16; r++) accO[df][sni][r] = 0.f;
  float mrun[2] = {-1.0e30f, -1.0e30f};
  float lrun[2] = {0.f, 0.f};

  for (int tile = 0; tile < 32; ++tile) {
    // ===== S^T = K · Q  (C: col = q (lane&31), rows = kv) =====
    f32x16 S[2][2];
#pragma unroll
    for (int smi = 0; smi < 2; smi++)
#pragma unroll
      for (int sni = 0; sni < 2; sni++)
#pragma unroll
        for (int r = 0; r < 16; r++) S[smi][sni][r] = 0.f;
#pragma unroll
    for (int kk = 0; kk < 5; kk++) {
      bf16x8 Kf[2];
#pragma unroll
      for (int smi = 0; smi < 2; smi++) {
        int kr = smi * 32 + c;
        int g = (((kk & 1) * 2 + hi) ^ ((kr >> 1) & 3));
        Kf[smi] = *(const bf16x8*)&sK[(kk >> 1) * 2048 + kr * 32 + g * 8];
      }
#pragma unroll
      for (int smi = 0; smi < 2; smi++)
#pragma unroll
        for (int sni = 0; sni < 2; sni++)
          S[smi][sni] = __builtin_amdgcn_mfma_f32_32x32x16_bf16(Kf[smi], Qf[sni][kk], S[smi][sni], 0, 0, 0);
    }

    // ===== online softmax (exp2 domain), per q column =====
#pragma unroll
    for (int sni = 0; sni < 2; sni++) {
      float mx = -1.0e30f;
#pragma unroll
      for (int smi = 0; smi < 2; smi++)
#pragma unroll
        for (int r = 0; r < 16; r++) mx = fmaxf(mx, S[smi][sni][r]);
      mx = fmaxf(mx, __shfl_xor(mx, 32, 64));
      if (__any(mx > mrun[sni] + 8.f)) {       // defer-max (T13)
        float mn = fmaxf(mrun[sni], mx);
        float al = exp2f(mrun[sni] - mn);
        lrun[sni] *= al;
#pragma unroll
        for (int df = 0; df < 3; df++)
#pragma unroll
          for (int r = 0; r < 16; r++) accO[df][sni][r] *= al;
        mrun[sni] = mn;
      }
      float rs = 0.f;
#pragma unroll
      for (int smi = 0; smi < 2; smi++)
#pragma unroll
        for (int r = 0; r < 16; r++) {
          float p = exp2f(S[smi][sni][r] - mrun[sni]);
          S[smi][sni][r] = p;
          rs += p;
        }
      rs += __shfl_xor(rs, 32, 64);
      lrun[sni] += rs;
    }

    // ===== O^T += V^T · P^T  (P^T built in-register) =====
#pragma unroll
    for (int kk = 0; kk < 4; kk++) {
      bf16x8 Vf[3];
#pragma unroll
      for (int df = 0; df < 3; df++) {
        int dr = df * 32 + c;
        int g = ((kk * 2 + hi) ^ (dr & 7));
        Vf[df] = *(const bf16x8*)&sV[dr * 64 + g * 8];
      }
#pragma unroll
      for (int sni = 0; sni < 2; sni++) {
        const int smi = kk >> 1;
        const int base = (kk & 1) * 8;
        unsigned u0 = pk2(S[smi][sni][base + 0], S[smi][sni][base + 1]);
        unsigned u1 = pk2(S[smi][sni][base + 2], S[smi][sni][base + 3]);
        unsigned u2 = pk2(S[smi][sni][base + 4], S[smi][sni][base + 5]);
        unsigned u3 = pk2(S[smi][sni][base + 6], S[smi][sni][base + 7]);
        unsigned sA = hi ? u0 : u2, sB = hi ? u1 : u3;
        unsigned rA = (unsigned)__shfl_xor((int)sA, 32, 64);
        unsigned rB = (unsigned)__shfl_xor((int)sB, 32, 64);
        union { bf16x8 v; unsigned u[4]; } pb;
        pb.u[0] = hi ? rA : u0;
        pb.u[1] = hi ? rB : u1;
        pb.u[2] = hi ? u2 : rA;
        pb.u[3] = hi ? u3 : rB;
#pragma unroll
        for (int df = 0; df < 3; df++)
          accO[df][sni] = __builtin_amdgcn_mfma_f32_32x32x16_bf16(Vf[df], pb.v, accO[df][sni], 0, 0, 0);
      }
    }

    __syncthreads();
    if (tile + 1 < 32) {
      int kv0 = (tile + 1) * 64;
#pragma unroll
      for (int i = 0; i < 3; i++) {
        int ch = wave * 3 + i;
        int kk = ch >> 2;
        int r = (ch & 3) * 16 + (lane >> 2);
        int g = (lane & 3) ^ ((r >> 1) & 3);
        gload16(Kb + (size_t)kk * (SEGL * 32) + (size_t)(kv0 + r) * 32 + g * 8,
                (char*)sK + ch * 1024);
      }
#pragma unroll
      for (int i = 0; i < 3; i++) {
        int ch = wave * 3 + i;
        int r = ch * 8 + (lane >> 3);
        int g = (lane & 7) ^ (r & 7);
        gload16(Vb + (size_t)r * SEGL + kv0 + g * 8, (char*)sV + ch * 1024);
      }
      __syncthreads();
    }
  }

  // ===== write O (token-major), 8 B packed stores =====
#pragma unroll
  for (int sni = 0; sni < 2; sni++) {
    float inv = 1.f / lrun[sni];
    int token = s * SEGL + q0 + wave * 64 + sni * 32 + c;
#pragma unroll
    for (int df = 0; df < 3; df++)
#pragma unroll
      for (int rg = 0; rg < 4; rg++) {
        int d0 = df * 32 + rg * 8 + hi * 4;
        if (d0 < HD) {
          ushort4_t w;
          w[0] = __builtin_bit_cast(unsigned short, (bf16)(accO[df][sni][rg * 4 + 0] * inv));
          w[1] = __builtin_bit_cast(unsigned short, (bf16)(accO[df][sni][rg * 4 + 1] * inv));
          w[2] = __builtin_bit_cast(unsigned short, (bf16)(accO[df][sni][rg * 4 + 2] * inv));
          w[3] = __builtin_bit_cast(unsigned short, (bf16)(accO[df][sni][rg * 4 + 3] * inv));
          *(ushort4_t*)&Oo[(size_t)token * DIMM + h * HD + d0] = w;
        }
      }
  }
}

// -------------------------------------------------------------------------------
extern "C" void kernel_launch(void* const* d_in, const int* in_sizes, int n_in,
                              void* d_out, int out_size, void* d_ws, size_t ws_size,
                              hipStream_t stream) {
  (void)in_sizes; (void)n_in; (void)out_size; (void)ws_size;
  const float* hs     = (const float*)d_in[0];
  const float* cosp   = (const float*)d_in[1];
  const float* sinp   = (const float*)d_in[2];
  const float* w_qkv  = (const float*)d_in[4];
  const float* b_qkv  = (const float*)d_in[5];
  const float* w_proj = (const float*)d_in[6];
  const float* b_proj = (const float*)d_in[7];
  float* out = (float*)d_out;

  char* ws = (char*)d_ws;
  bf16* hsb    = (bf16*)(ws + 0);          // 18874368
  bf16* wqkvT  = (bf16*)(ws + 18874368);   //  7962624
  bf16* wprojT = (bf16*)(ws + 26836992);   //  2654208
  bf16* qkv    = (bf16*)(ws + 29491200);   // 56623104
  bf16* Qp     = (bf16*)(ws + 86114304);   // 25165824
  bf16* Kp     = (bf16*)(ws + 111280128);  // 25165824
  bf16* Vt     = (bf16*)(ws + 136445952);  // 25165824
  bf16* ao     = (bf16*)(ws + 161611776);  // 18874368

  k_cvt<<<4608, 256, 0, stream>>>(hs, hsb, 1179648);
  k_twt<<<dim3(54, 18), 256, 0, stream>>>(w_qkv, wqkvT, 1152, 3456);
  k_twt<<<dim3(18, 18), 256, 0, stream>>>(w_proj, wprojT, 1152, 1152);
  k_gemm<false><<<dim3(27, 64), 256, 0, stream>>>(hsb, wqkvT, b_qkv, (void*)qkv, 8192, 3456, 1152);
  k_rope<<<8192, 256, 0, stream>>>(qkv, cosp, sinp, Qp, Kp);
  k_vrep<<<dim3(32, 16, 4), 256, 0, stream>>>(qkv, Vt);
  k_attn<<<dim3(8, 16, 4), 256, 0, stream>>>(Qp, Kp, Vt, ao);
  k_gemm<true><<<dim3(9, 64), 256, 0, stream>>>(ao, wprojT, b_proj, (void*)out, 8192, 1152, 1152);
}

// Round 3
// 360.497 us; speedup vs baseline: 1.4732x; 1.1127x over previous
//
#include <hip/hip_runtime.h>
#include <hip/hip_bf16.h>
#include <cstdint>
#include <cstddef>

typedef __bf16 bf16;
typedef __attribute__((ext_vector_type(8))) __bf16 bf16x8;
typedef __attribute__((ext_vector_type(4))) float f32x4;
typedef __attribute__((ext_vector_type(16))) float f32x16;
typedef __attribute__((ext_vector_type(4))) float floatx4;
typedef __attribute__((ext_vector_type(4))) unsigned short ushort4_t;

// Problem constants
#define NTOK 8192
#define DIMM 1152
#define NH   16
#define HD   72
#define SEGS 4
#define SEGL 2048

__device__ __forceinline__ void gload16(const void* gsrc, void* ldst) {
  __builtin_amdgcn_global_load_lds(
      (const __attribute__((address_space(1))) void*)gsrc,
      (__attribute__((address_space(3))) void*)ldst,
      16, 0, 0);
}

__device__ __forceinline__ unsigned pk2(float a, float b) {
  unsigned short x = __builtin_bit_cast(unsigned short, (bf16)a);
  unsigned short y = __builtin_bit_cast(unsigned short, (bf16)b);
  return (unsigned)x | ((unsigned)y << 16);
}

// ---------------- f32 -> bf16 elementwise convert (8 elems/thread) -------------
__global__ __launch_bounds__(256) void k_cvt(const float* __restrict__ src,
                                             bf16* __restrict__ dst, int n8) {
  int i = blockIdx.x * 256 + threadIdx.x;
  if (i >= n8) return;
  const floatx4* s = (const floatx4*)src + (size_t)i * 2;
  floatx4 a = s[0], b = s[1];
  bf16x8 o;
  o[0] = (bf16)a.x; o[1] = (bf16)a.y; o[2] = (bf16)a.z; o[3] = (bf16)a.w;
  o[4] = (bf16)b.x; o[5] = (bf16)b.y; o[6] = (bf16)b.z; o[7] = (bf16)b.w;
  *((bf16x8*)dst + i) = o;
}

// ---------------- transpose + convert: src[R][C] f32 -> dst[C][R] bf16 ---------
__global__ __launch_bounds__(256) void k_twt(const float* __restrict__ src,
                                             bf16* __restrict__ dst, int R, int C) {
  __shared__ bf16 tile[64][73];
  int bc = blockIdx.x * 64, br = blockIdx.y * 64;
  int t = threadIdx.x;
#pragma unroll
  for (int i = 0; i < 16; i++) {
    int idx = i * 256 + t;
    int r = idx >> 6, c = idx & 63;
    tile[c][r] = (bf16)src[(size_t)(br + r) * C + bc + c];
  }
  __syncthreads();
#pragma unroll
  for (int i = 0; i < 16; i++) {
    int idx = i * 256 + t;
    int r = idx >> 6, c = idx & 63;
    dst[(size_t)(bc + r) * R + br + c] = tile[r][c];
  }
}

// ------------- bf16 GEMM 128x128 (proj): C = A * Bt^T + bias, XCD swizzle ------
template <bool OUT_F32>
__global__ __launch_bounds__(256) void k_gemm(const bf16* __restrict__ A,
                                              const bf16* __restrict__ Bt,
                                              const float* __restrict__ bias,
                                              void* __restrict__ Cout,
                                              int M, int N, int K, int gx) {
  __shared__ bf16 sA[128 * 64];
  __shared__ bf16 sB[128 * 64];
  const int t = threadIdx.x, wave = t >> 6, lane = t & 63;
  const int lr = lane & 15, lg = lane >> 4;
  const int nwg = gridDim.x, bid = blockIdx.x;
  const int swz = (bid & 7) * (nwg >> 3) + (bid >> 3);
  const int bx = swz % gx, by = swz / gx;
  const int m0 = by * 128, n0 = bx * 128;
  const int wm = (wave >> 1) * 64, wn = (wave & 1) * 64;
  f32x4 acc[4][4];
#pragma unroll
  for (int i = 0; i < 4; i++)
#pragma unroll
    for (int j = 0; j < 4; j++)
#pragma unroll
      for (int q = 0; q < 4; q++) acc[i][j][q] = 0.f;

  const bf16* Ab = A + (size_t)m0 * K;
  const bf16* Bb = Bt + (size_t)n0 * K;

  for (int k0 = 0; k0 < K; k0 += 64) {
#pragma unroll
    for (int it = 0; it < 4; ++it) {
      int e = it * 2048 + t * 8;
      int r = e >> 6, c = e & 63;
      gload16(Ab + (size_t)r * K + (k0 + c), (char*)sA + it * 4096 + wave * 1024);
      gload16(Bb + (size_t)r * K + (k0 + c), (char*)sB + it * 4096 + wave * 1024);
    }
    __syncthreads();
#pragma unroll
    for (int kk = 0; kk < 2; ++kk) {
      bf16x8 av[4], bv[4];
#pragma unroll
      for (int mi = 0; mi < 4; ++mi)
        av[mi] = *(const bf16x8*)&sA[(wm + mi * 16 + lr) * 64 + kk * 32 + lg * 8];
#pragma unroll
      for (int ni = 0; ni < 4; ++ni)
        bv[ni] = *(const bf16x8*)&sB[(wn + ni * 16 + lr) * 64 + kk * 32 + lg * 8];
#pragma unroll
      for (int mi = 0; mi < 4; ++mi)
#pragma unroll
        for (int ni = 0; ni < 4; ++ni)
          acc[mi][ni] = __builtin_amdgcn_mfma_f32_16x16x32_bf16(av[mi], bv[ni], acc[mi][ni], 0, 0, 0);
    }
    __syncthreads();
  }
#pragma unroll
  for (int mi = 0; mi < 4; ++mi)
#pragma unroll
    for (int ni = 0; ni < 4; ++ni) {
      int col = n0 + wn + ni * 16 + lr;
      float bc_ = bias[col];
#pragma unroll
      for (int j = 0; j < 4; j++) {
        int row = m0 + wm + mi * 16 + lg * 4 + j;
        float v = acc[mi][ni][j] + bc_;
        if (OUT_F32)
          ((float*)Cout)[(size_t)row * N + col] = v;
        else
          ((bf16*)Cout)[(size_t)row * N + col] = (bf16)v;
      }
    }
}

// ------------- bf16 GEMM 256x128, 8 waves (QKV): C bf16 = A * Bt^T + bias ------
__global__ __launch_bounds__(512) void k_gemm256(const bf16* __restrict__ A,
                                                 const bf16* __restrict__ Bt,
                                                 const float* __restrict__ bias,
                                                 bf16* __restrict__ C,
                                                 int M, int N, int K, int gx) {
  __shared__ bf16 sA[256 * 64];
  __shared__ bf16 sB[128 * 64];
  const int t = threadIdx.x, wave = t >> 6, lane = t & 63;
  const int lr = lane & 15, lg = lane >> 4;
  const int nwg = gridDim.x, bid = blockIdx.x;
  const int swz = (bid & 7) * (nwg >> 3) + (bid >> 3);
  const int bx = swz % gx, by = swz / gx;
  const int m0 = by * 256, n0 = bx * 128;
  const int wm = (wave >> 1) * 64, wn = (wave & 1) * 64;
  f32x4 acc[4][4];
#pragma unroll
  for (int i = 0; i < 4; i++)
#pragma unroll
    for (int j = 0; j < 4; j++)
#pragma unroll
      for (int q = 0; q < 4; q++) acc[i][j][q] = 0.f;

  const bf16* Ab = A + (size_t)m0 * K;
  const bf16* Bb = Bt + (size_t)n0 * K;

  for (int k0 = 0; k0 < K; k0 += 64) {
#pragma unroll
    for (int it = 0; it < 4; ++it) {
      int e = it * 4096 + t * 8;        // [256][64] A tile
      int r = e >> 6, c = e & 63;
      gload16(Ab + (size_t)r * K + (k0 + c), (char*)sA + it * 8192 + wave * 1024);
    }
#pragma unroll
    for (int it = 0; it < 2; ++it) {
      int e = it * 4096 + t * 8;        // [128][64] B tile
      int r = e >> 6, c = e & 63;
      gload16(Bb + (size_t)r * K + (k0 + c), (char*)sB + it * 8192 + wave * 1024);
    }
    __syncthreads();
#pragma unroll
    for (int kk = 0; kk < 2; ++kk) {
      bf16x8 av[4], bv[4];
#pragma unroll
      for (int mi = 0; mi < 4; ++mi)
        av[mi] = *(const bf16x8*)&sA[(wm + mi * 16 + lr) * 64 + kk * 32 + lg * 8];
#pragma unroll
      for (int ni = 0; ni < 4; ++ni)
        bv[ni] = *(const bf16x8*)&sB[(wn + ni * 16 + lr) * 64 + kk * 32 + lg * 8];
#pragma unroll
      for (int mi = 0; mi < 4; ++mi)
#pragma unroll
        for (int ni = 0; ni < 4; ++ni)
          acc[mi][ni] = __builtin_amdgcn_mfma_f32_16x16x32_bf16(av[mi], bv[ni], acc[mi][ni], 0, 0, 0);
    }
    __syncthreads();
  }
#pragma unroll
  for (int mi = 0; mi < 4; ++mi)
#pragma unroll
    for (int ni = 0; ni < 4; ++ni) {
      int col = n0 + wn + ni * 16 + lr;
      float bc_ = bias[col];
#pragma unroll
      for (int j = 0; j < 4; j++) {
        int row = m0 + wm + mi * 16 + lg * 4 + j;
        C[(size_t)row * N + col] = (bf16)(acc[mi][ni][j] + bc_);
      }
    }
}

// ---------------- RoPE + repack Q,K: qkv[n][3456] -> Qp/Kp[s][h][3][2048][32] --
// Q is pre-scaled by log2(e)/sqrt(72) so attention works in exp2 domain.
__global__ __launch_bounds__(256) void k_rope(const bf16* __restrict__ qkv,
                                              const float* __restrict__ cs,
                                              const float* __restrict__ sn,
                                              bf16* __restrict__ Qp,
                                              bf16* __restrict__ Kp) {
  int n = blockIdx.x;
  int s = n >> 11, l = n & 2047;
  const bf16* row = qkv + (size_t)n * (3 * DIMM);
  const float* cr = cs + (size_t)n * HD;
  const float* sr = sn + (size_t)n * HD;
  const float QS = 0.17002323f;  // log2(e)/sqrt(72)
  for (int e = threadIdx.x; e < 3072; e += 256) {
    int which = e / 1536;             // 0=q, 1=k
    int r = e - which * 1536;
    int h = r / 96;
    int d = r - h * 96;
    float v = 0.f;
    if (d < HD) {
      int base = which * DIMM + h * HD;
      float x = (float)row[base + d];
      float o = (d < 36) ? -(float)row[base + d + 36] : (float)row[base + d - 36];
      v = x * cr[d] + o * sr[d];
      if (which == 0) v *= QS;
    }
    bf16* dst = which ? Kp : Qp;
    dst[(((size_t)(s * NH + h) * 3 + (d >> 5)) * SEGL + l) * 32 + (d & 31)] = (bf16)v;
  }
}

// ---------------- V repack (transpose): qkv v-part -> Vt[s][h][96][2048] -------
__global__ __launch_bounds__(256) void k_vrep(const bf16* __restrict__ qkv,
                                              bf16* __restrict__ Vt) {
  int s = blockIdx.z, h = blockIdx.y, l0 = blockIdx.x * 64;
  __shared__ bf16 tl[64][73];
  int t = threadIdx.x;
  for (int idx = t; idx < 64 * HD; idx += 256) {
    int l = idx / HD, d = idx - l * HD;
    tl[l][d] = qkv[(size_t)(s * SEGL + l0 + l) * (3 * DIMM) + 2 * DIMM + h * HD + d];
  }
  __syncthreads();
  for (int idx = t; idx < 96 * 64; idx += 256) {
    int d = idx >> 6, l = idx & 63;
    bf16 v = (d < HD) ? tl[l][d] : (bf16)0.f;
    Vt[((size_t)(s * NH + h) * 96 + d) * SEGL + l0 + l] = v;
  }
}

// ---------------- flash attention, swapped-operand 32x32 MFMA ------------------
// 4 waves x 64 q-rows = 256-q tile. Q fragments loaded straight to registers.
// K/V tiles double-buffered in LDS; next-tile staging issued BEFORE compute so
// HBM latency hides under S/softmax/PV; ONE barrier per tile.
__global__ __launch_bounds__(256, 2) void k_attn(const bf16* __restrict__ Qg,
                                                 const bf16* __restrict__ Kg,
                                                 const bf16* __restrict__ Vg,
                                                 bf16* __restrict__ Oo) {
  __shared__ bf16 sK[2][3 * 64 * 32];   // 2 x 12 KB
  __shared__ bf16 sV[2][96 * 64];       // 2 x 12 KB
  const int t = threadIdx.x, wave = t >> 6, lane = t & 63;
  const int c = lane & 31, hi = lane >> 5;
  const int s = blockIdx.z, h = blockIdx.y, q0 = blockIdx.x * 256;
  const bf16* Qb = Qg + (size_t)(s * NH + h) * 3 * SEGL * 32;
  const bf16* Kb = Kg + (size_t)(s * NH + h) * 3 * SEGL * 32;
  const bf16* Vb = Vg + (size_t)(s * NH + h) * 96 * SEGL;

  // ---- Q fragments: direct global -> registers (constant across kv tiles) ----
  bf16x8 Qf[2][5];
#pragma unroll
  for (int sni = 0; sni < 2; sni++)
#pragma unroll
    for (int kk = 0; kk < 5; kk++) {
      int qr = q0 + wave * 64 + sni * 32 + c;
      Qf[sni][kk] = *(const bf16x8*)&Qb[(size_t)(kk >> 1) * (SEGL * 32) +
                                        (size_t)qr * 32 + ((kk & 1) * 2 + hi) * 8];
    }

  // ---- stage K,V tile 0 into buffer 0 ----
#pragma unroll
  for (int i = 0; i < 3; i++) {
    int ch = wave * 3 + i;
    int kk = ch >> 2;
    int r = (ch & 3) * 16 + (lane >> 2);
    int g = (lane & 3) ^ ((r >> 1) & 3);
    gload16(Kb + (size_t)kk * (SEGL * 32) + (size_t)r * 32 + g * 8,
            (char*)sK[0] + ch * 1024);
  }
#pragma unroll
  for (int i = 0; i < 3; i++) {
    int ch = wave * 3 + i;
    int r = ch * 8 + (lane >> 3);
    int g = (lane & 7) ^ (r & 7);
    gload16(Vb + (size_t)r * SEGL + g * 8, (char*)sV[0] + ch * 1024);
  }
  __syncthreads();

  f32x16 accO[3][2];
#pragma unroll
  for (int df = 0; df < 3; df++)
#pragma unroll
    for (int sni = 0; sni < 2; sni++)
#pragma unroll
      for (int r = 0; r < 16; r++) accO[df][sni][r] = 0.f;
  float mrun[2] = {-1.0e30f, -1.0e30f};
  float lrun[2] = {0.f, 0.f};

  int cur = 0;
  for (int tile = 0; tile < 32; ++tile) {
    // ---- issue next-tile staging into the other buffer (overlaps compute) ----
    if (tile + 1 < 32) {
      int kv0 = (tile + 1) * 64;
#pragma unroll
      for (int i = 0; i < 3; i++) {
        int ch = wave * 3 + i;
        int kk = ch >> 2;
        int r = (ch & 3) * 16 + (lane >> 2);
        int g = (lane & 3) ^ ((r >> 1) & 3);
        gload16(Kb + (size_t)kk * (SEGL * 32) + (size_t)(kv0 + r) * 32 + g * 8,
                (char*)sK[cur ^ 1] + ch * 1024);
      }
#pragma unroll
      for (int i = 0; i < 3; i++) {
        int ch = wave * 3 + i;
        int r = ch * 8 + (lane >> 3);
        int g = (lane & 7) ^ (r & 7);
        gload16(Vb + (size_t)r * SEGL + kv0 + g * 8, (char*)sV[cur ^ 1] + ch * 1024);
      }
    }

    // ===== S^T = K · Q  (C: col = q (lane&31), rows = kv) =====
    f32x16 S[2][2];
#pragma unroll
    for (int smi = 0; smi < 2; smi++)
#pragma unroll
      for (int sni = 0; sni < 2; sni++)
#pragma unroll
        for (int r = 0; r < 16; r++) S[smi][sni][r] = 0.f;
    __builtin_amdgcn_s_setprio(1);
#pragma unroll
    for (int kk = 0; kk < 5; kk++) {
      bf16x8 Kf[2];
#pragma unroll
      for (int smi = 0; smi < 2; smi++) {
        int kr = smi * 32 + c;
        int g = (((kk & 1) * 2 + hi) ^ ((kr >> 1) & 3));
        Kf[smi] = *(const bf16x8*)&sK[cur][(kk >> 1) * 2048 + kr * 32 + g * 8];
      }
#pragma unroll
      for (int smi = 0; smi < 2; smi++)
#pragma unroll
        for (int sni = 0; sni < 2; sni++)
          S[smi][sni] = __builtin_amdgcn_mfma_f32_32x32x16_bf16(Kf[smi], Qf[sni][kk], S[smi][sni], 0, 0, 0);
    }
    __builtin_amdgcn_s_setprio(0);

    // ===== online softmax (exp2 domain), per q column =====
#pragma unroll
    for (int sni = 0; sni < 2; sni++) {
      float mx = -1.0e30f;
#pragma unroll
      for (int smi = 0; smi < 2; smi++)
#pragma unroll
        for (int r = 0; r < 16; r++) mx = fmaxf(mx, S[smi][sni][r]);
      mx = fmaxf(mx, __shfl_xor(mx, 32, 64));
      if (__any(mx > mrun[sni] + 8.f)) {       // defer-max (T13)
        float mn = fmaxf(mrun[sni], mx);
        float al = exp2f(mrun[sni] - mn);
        lrun[sni] *= al;
#pragma unroll
        for (int df = 0; df < 3; df++)
#pragma unroll
          for (int r = 0; r < 16; r++) accO[df][sni][r] *= al;
        mrun[sni] = mn;
      }
      float rs = 0.f;
#pragma unroll
      for (int smi = 0; smi < 2; smi++)
#pragma unroll
        for (int r = 0; r < 16; r++) {
          float p = exp2f(S[smi][sni][r] - mrun[sni]);
          S[smi][sni][r] = p;
          rs += p;
        }
      rs += __shfl_xor(rs, 32, 64);
      lrun[sni] += rs;
    }

    // ===== O^T += V^T · P^T  (P^T built in-register) =====
    __builtin_amdgcn_s_setprio(1);
#pragma unroll
    for (int kk = 0; kk < 4; kk++) {
      bf16x8 Vf[3];
#pragma unroll
      for (int df = 0; df < 3; df++) {
        int dr = df * 32 + c;
        int g = ((kk * 2 + hi) ^ (dr & 7));
        Vf[df] = *(const bf16x8*)&sV[cur][dr * 64 + g * 8];
      }
#pragma unroll
      for (int sni = 0; sni < 2; sni++) {
        const int smi = kk >> 1;
        const int base = (kk & 1) * 8;
        unsigned u0 = pk2(S[smi][sni][base + 0], S[smi][sni][base + 1]);
        unsigned u1 = pk2(S[smi][sni][base + 2], S[smi][sni][base + 3]);
        unsigned u2 = pk2(S[smi][sni][base + 4], S[smi][sni][base + 5]);
        unsigned u3 = pk2(S[smi][sni][base + 6], S[smi][sni][base + 7]);
        unsigned sA_ = hi ? u0 : u2, sB_ = hi ? u1 : u3;
        unsigned rA = (unsigned)__shfl_xor((int)sA_, 32, 64);
        unsigned rB = (unsigned)__shfl_xor((int)sB_, 32, 64);
        union { bf16x8 v; unsigned u[4]; } pb;
        pb.u[0] = hi ? rA : u0;
        pb.u[1] = hi ? rB : u1;
        pb.u[2] = hi ? u2 : rA;
        pb.u[3] = hi ? u3 : rB;
#pragma unroll
        for (int df = 0; df < 3; df++)
          accO[df][sni] = __builtin_amdgcn_mfma_f32_32x32x16_bf16(Vf[df], pb.v, accO[df][sni], 0, 0, 0);
      }
    }
    __builtin_amdgcn_s_setprio(0);

    // one barrier per tile: drains this thread's staging loads (vmcnt) too
    __syncthreads();
    cur ^= 1;
  }

  // ===== write O (token-major), 8 B packed stores =====
#pragma unroll
  for (int sni = 0; sni < 2; sni++) {
    float inv = 1.f / lrun[sni];
    int token = s * SEGL + q0 + wave * 64 + sni * 32 + c;
#pragma unroll
    for (int df = 0; df < 3; df++)
#pragma unroll
      for (int rg = 0; rg < 4; rg++) {
        int d0 = df * 32 + rg * 8 + hi * 4;
        if (d0 < HD) {
          ushort4_t w;
          w[0] = __builtin_bit_cast(unsigned short, (bf16)(accO[df][sni][rg * 4 + 0] * inv));
          w[1] = __builtin_bit_cast(unsigned short, (bf16)(accO[df][sni][rg * 4 + 1] * inv));
          w[2] = __builtin_bit_cast(unsigned short, (bf16)(accO[df][sni][rg * 4 + 2] * inv));
          w[3] = __builtin_bit_cast(unsigned short, (bf16)(accO[df][sni][rg * 4 + 3] * inv));
          *(ushort4_t*)&Oo[(size_t)token * DIMM + h * HD + d0] = w;
        }
      }
  }
}

// -------------------------------------------------------------------------------
extern "C" void kernel_launch(void* const* d_in, const int* in_sizes, int n_in,
                              void* d_out, int out_size, void* d_ws, size_t ws_size,
                              hipStream_t stream) {
  (void)in_sizes; (void)n_in; (void)out_size; (void)ws_size;
  const float* hs     = (const float*)d_in[0];
  const float* cosp   = (const float*)d_in[1];
  const float* sinp   = (const float*)d_in[2];
  const float* w_qkv  = (const float*)d_in[4];
  const float* b_qkv  = (const float*)d_in[5];
  const float* w_proj = (const float*)d_in[6];
  const float* b_proj = (const float*)d_in[7];
  float* out = (float*)d_out;

  char* ws = (char*)d_ws;
  bf16* hsb    = (bf16*)(ws + 0);          // 18874368
  bf16* wqkvT  = (bf16*)(ws + 18874368);   //  7962624
  bf16* wprojT = (bf16*)(ws + 26836992);   //  2654208
  bf16* qkv    = (bf16*)(ws + 29491200);   // 56623104
  bf16* Qp     = (bf16*)(ws + 86114304);   // 25165824
  bf16* Kp     = (bf16*)(ws + 111280128);  // 25165824
  bf16* Vt     = (bf16*)(ws + 136445952);  // 25165824
  bf16* ao     = (bf16*)(ws + 161611776);  // 18874368

  k_cvt<<<4608, 256, 0, stream>>>(hs, hsb, 1179648);
  k_twt<<<dim3(54, 18), 256, 0, stream>>>(w_qkv, wqkvT, 1152, 3456);
  k_twt<<<dim3(18, 18), 256, 0, stream>>>(w_proj, wprojT, 1152, 1152);
  k_gemm256<<<864, 512, 0, stream>>>(hsb, wqkvT, b_qkv, qkv, 8192, 3456, 1152, 27);
  k_rope<<<8192, 256, 0, stream>>>(qkv, cosp, sinp, Qp, Kp);
  k_vrep<<<dim3(32, 16, 4), 256, 0, stream>>>(qkv, Vt);
  k_attn<<<dim3(8, 16, 4), 256, 0, stream>>>(Qp, Kp, Vt, ao);
  k_gemm<true><<<576, 256, 0, stream>>>(ao, wprojT, b_proj, (void*)out, 8192, 1152, 1152, 9);
}

// Round 4
// 316.794 us; speedup vs baseline: 1.6765x; 1.1380x over previous
//
#include <hip/hip_runtime.h>
#include <hip/hip_bf16.h>
#include <cstdint>
#include <cstddef>

typedef __bf16 bf16;
typedef __attribute__((ext_vector_type(8))) __bf16 bf16x8;
typedef __attribute__((ext_vector_type(4))) float f32x4;
typedef __attribute__((ext_vector_type(16))) float f32x16;
typedef __attribute__((ext_vector_type(4))) float floatx4;
typedef __attribute__((ext_vector_type(4))) unsigned short ushort4_t;

// Problem constants
#define NTOK 8192
#define DIMM 1152
#define NH   16
#define HD   72
#define SEGS 4
#define SEGL 2048

__device__ __forceinline__ void gload16(const void* gsrc, void* ldst) {
  __builtin_amdgcn_global_load_lds(
      (const __attribute__((address_space(1))) void*)gsrc,
      (__attribute__((address_space(3))) void*)ldst,
      16, 0, 0);
}

__device__ __forceinline__ unsigned pk2(float a, float b) {
  unsigned short x = __builtin_bit_cast(unsigned short, (bf16)a);
  unsigned short y = __builtin_bit_cast(unsigned short, (bf16)b);
  return (unsigned)x | ((unsigned)y << 16);
}

// ---------------- f32 -> bf16 elementwise convert (8 elems/thread) -------------
__global__ __launch_bounds__(256) void k_cvt(const float* __restrict__ src,
                                             bf16* __restrict__ dst, int n8) {
  int i = blockIdx.x * 256 + threadIdx.x;
  if (i >= n8) return;
  const floatx4* s = (const floatx4*)src + (size_t)i * 2;
  floatx4 a = s[0], b = s[1];
  bf16x8 o;
  o[0] = (bf16)a.x; o[1] = (bf16)a.y; o[2] = (bf16)a.z; o[3] = (bf16)a.w;
  o[4] = (bf16)b.x; o[5] = (bf16)b.y; o[6] = (bf16)b.z; o[7] = (bf16)b.w;
  *((bf16x8*)dst + i) = o;
}

// ---------------- transpose + convert: src[R][C] f32 -> dst[C][R] bf16 ---------
__global__ __launch_bounds__(256) void k_twt(const float* __restrict__ src,
                                             bf16* __restrict__ dst, int R, int C) {
  __shared__ bf16 tile[64][73];
  int bc = blockIdx.x * 64, br = blockIdx.y * 64;
  int t = threadIdx.x;
#pragma unroll
  for (int i = 0; i < 16; i++) {
    int idx = i * 256 + t;
    int r = idx >> 6, c = idx & 63;
    tile[c][r] = (bf16)src[(size_t)(br + r) * C + bc + c];
  }
  __syncthreads();
#pragma unroll
  for (int i = 0; i < 16; i++) {
    int idx = i * 256 + t;
    int r = idx >> 6, c = idx & 63;
    dst[(size_t)(bc + r) * R + br + c] = tile[r][c];
  }
}

// ------------- bf16 GEMM 128x128 (proj): C = A * Bt^T + bias, XCD swizzle ------
template <bool OUT_F32>
__global__ __launch_bounds__(256) void k_gemm(const bf16* __restrict__ A,
                                              const bf16* __restrict__ Bt,
                                              const float* __restrict__ bias,
                                              void* __restrict__ Cout,
                                              int M, int N, int K, int gx) {
  __shared__ bf16 sA[128 * 64];
  __shared__ bf16 sB[128 * 64];
  const int t = threadIdx.x, wave = t >> 6, lane = t & 63;
  const int lr = lane & 15, lg = lane >> 4;
  const int nwg = gridDim.x, bid = blockIdx.x;
  const int swz = (bid & 7) * (nwg >> 3) + (bid >> 3);
  const int bx = swz % gx, by = swz / gx;
  const int m0 = by * 128, n0 = bx * 128;
  const int wm = (wave >> 1) * 64, wn = (wave & 1) * 64;
  f32x4 acc[4][4];
#pragma unroll
  for (int i = 0; i < 4; i++)
#pragma unroll
    for (int j = 0; j < 4; j++)
#pragma unroll
      for (int q = 0; q < 4; q++) acc[i][j][q] = 0.f;

  const bf16* Ab = A + (size_t)m0 * K;
  const bf16* Bb = Bt + (size_t)n0 * K;

  for (int k0 = 0; k0 < K; k0 += 64) {
#pragma unroll
    for (int it = 0; it < 4; ++it) {
      int e = it * 2048 + t * 8;
      int r = e >> 6, c = e & 63;
      gload16(Ab + (size_t)r * K + (k0 + c), (char*)sA + it * 4096 + wave * 1024);
      gload16(Bb + (size_t)r * K + (k0 + c), (char*)sB + it * 4096 + wave * 1024);
    }
    __syncthreads();
#pragma unroll
    for (int kk = 0; kk < 2; ++kk) {
      bf16x8 av[4], bv[4];
#pragma unroll
      for (int mi = 0; mi < 4; ++mi)
        av[mi] = *(const bf16x8*)&sA[(wm + mi * 16 + lr) * 64 + kk * 32 + lg * 8];
#pragma unroll
      for (int ni = 0; ni < 4; ++ni)
        bv[ni] = *(const bf16x8*)&sB[(wn + ni * 16 + lr) * 64 + kk * 32 + lg * 8];
#pragma unroll
      for (int mi = 0; mi < 4; ++mi)
#pragma unroll
        for (int ni = 0; ni < 4; ++ni)
          acc[mi][ni] = __builtin_amdgcn_mfma_f32_16x16x32_bf16(av[mi], bv[ni], acc[mi][ni], 0, 0, 0);
    }
    __syncthreads();
  }
#pragma unroll
  for (int mi = 0; mi < 4; ++mi)
#pragma unroll
    for (int ni = 0; ni < 4; ++ni) {
      int col = n0 + wn + ni * 16 + lr;
      float bc_ = bias[col];
#pragma unroll
      for (int j = 0; j < 4; j++) {
        int row = m0 + wm + mi * 16 + lg * 4 + j;
        float v = acc[mi][ni][j] + bc_;
        if (OUT_F32)
          ((float*)Cout)[(size_t)row * N + col] = v;
        else
          ((bf16*)Cout)[(size_t)row * N + col] = (bf16)v;
      }
    }
}

// ------------- bf16 GEMM 256x128, 8 waves (QKV): C bf16 = A * Bt^T + bias ------
__global__ __launch_bounds__(512) void k_gemm256(const bf16* __restrict__ A,
                                                 const bf16* __restrict__ Bt,
                                                 const float* __restrict__ bias,
                                                 bf16* __restrict__ C,
                                                 int M, int N, int K, int gx) {
  __shared__ bf16 sA[256 * 64];
  __shared__ bf16 sB[128 * 64];
  const int t = threadIdx.x, wave = t >> 6, lane = t & 63;
  const int lr = lane & 15, lg = lane >> 4;
  const int nwg = gridDim.x, bid = blockIdx.x;
  const int swz = (bid & 7) * (nwg >> 3) + (bid >> 3);
  const int bx = swz % gx, by = swz / gx;
  const int m0 = by * 256, n0 = bx * 128;
  const int wm = (wave >> 1) * 64, wn = (wave & 1) * 64;
  f32x4 acc[4][4];
#pragma unroll
  for (int i = 0; i < 4; i++)
#pragma unroll
    for (int j = 0; j < 4; j++)
#pragma unroll
      for (int q = 0; q < 4; q++) acc[i][j][q] = 0.f;

  const bf16* Ab = A + (size_t)m0 * K;
  const bf16* Bb = Bt + (size_t)n0 * K;

  for (int k0 = 0; k0 < K; k0 += 64) {
#pragma unroll
    for (int it = 0; it < 4; ++it) {
      int e = it * 4096 + t * 8;        // [256][64] A tile
      int r = e >> 6, c = e & 63;
      gload16(Ab + (size_t)r * K + (k0 + c), (char*)sA + it * 8192 + wave * 1024);
    }
#pragma unroll
    for (int it = 0; it < 2; ++it) {
      int e = it * 4096 + t * 8;        // [128][64] B tile
      int r = e >> 6, c = e & 63;
      gload16(Bb + (size_t)r * K + (k0 + c), (char*)sB + it * 8192 + wave * 1024);
    }
    __syncthreads();
#pragma unroll
    for (int kk = 0; kk < 2; ++kk) {
      bf16x8 av[4], bv[4];
#pragma unroll
      for (int mi = 0; mi < 4; ++mi)
        av[mi] = *(const bf16x8*)&sA[(wm + mi * 16 + lr) * 64 + kk * 32 + lg * 8];
#pragma unroll
      for (int ni = 0; ni < 4; ++ni)
        bv[ni] = *(const bf16x8*)&sB[(wn + ni * 16 + lr) * 64 + kk * 32 + lg * 8];
#pragma unroll
      for (int mi = 0; mi < 4; ++mi)
#pragma unroll
        for (int ni = 0; ni < 4; ++ni)
          acc[mi][ni] = __builtin_amdgcn_mfma_f32_16x16x32_bf16(av[mi], bv[ni], acc[mi][ni], 0, 0, 0);
    }
    __syncthreads();
  }
#pragma unroll
  for (int mi = 0; mi < 4; ++mi)
#pragma unroll
    for (int ni = 0; ni < 4; ++ni) {
      int col = n0 + wn + ni * 16 + lr;
      float bc_ = bias[col];
#pragma unroll
      for (int j = 0; j < 4; j++) {
        int row = m0 + wm + mi * 16 + lg * 4 + j;
        C[(size_t)row * N + col] = (bf16)(acc[mi][ni][j] + bc_);
      }
    }
}

// ---------------- RoPE + repack Q,K: qkv[n][3456] -> Qp/Kp[s][h][3][2048][32] --
// Q is pre-scaled by log2(e)/sqrt(72) so attention works in exp2 domain.
__global__ __launch_bounds__(256) void k_rope(const bf16* __restrict__ qkv,
                                              const float* __restrict__ cs,
                                              const float* __restrict__ sn,
                                              bf16* __restrict__ Qp,
                                              bf16* __restrict__ Kp) {
  int n = blockIdx.x;
  int s = n >> 11, l = n & 2047;
  const bf16* row = qkv + (size_t)n * (3 * DIMM);
  const float* cr = cs + (size_t)n * HD;
  const float* sr = sn + (size_t)n * HD;
  const float QS = 0.17002323f;  // log2(e)/sqrt(72)
  for (int e = threadIdx.x; e < 3072; e += 256) {
    int which = e / 1536;             // 0=q, 1=k
    int r = e - which * 1536;
    int h = r / 96;
    int d = r - h * 96;
    float v = 0.f;
    if (d < HD) {
      int base = which * DIMM + h * HD;
      float x = (float)row[base + d];
      float o = (d < 36) ? -(float)row[base + d + 36] : (float)row[base + d - 36];
      v = x * cr[d] + o * sr[d];
      if (which == 0) v *= QS;
    }
    bf16* dst = which ? Kp : Qp;
    dst[(((size_t)(s * NH + h) * 3 + (d >> 5)) * SEGL + l) * 32 + (d & 31)] = (bf16)v;
  }
}

// ---------------- V repack (transpose): qkv v-part -> Vt[s][h][96][2048] -------
// Row HD (=72) is set to 1.0: the PV MFMA then accumulates the softmax
// denominator l = sum(P) for free into the d=72 output row.
__global__ __launch_bounds__(256) void k_vrep(const bf16* __restrict__ qkv,
                                              bf16* __restrict__ Vt) {
  int s = blockIdx.z, h = blockIdx.y, l0 = blockIdx.x * 64;
  __shared__ bf16 tl[64][73];
  int t = threadIdx.x;
  for (int idx = t; idx < 64 * HD; idx += 256) {
    int l = idx / HD, d = idx - l * HD;
    tl[l][d] = qkv[(size_t)(s * SEGL + l0 + l) * (3 * DIMM) + 2 * DIMM + h * HD + d];
  }
  __syncthreads();
  for (int idx = t; idx < 96 * 64; idx += 256) {
    int d = idx >> 6, l = idx & 63;
    bf16 v = (d < HD) ? tl[l][d] : ((d == HD) ? (bf16)1.f : (bf16)0.f);
    Vt[((size_t)(s * NH + h) * 96 + d) * SEGL + l0 + l] = v;
  }
}

// ---------------- flash attention, swapped-operand 32x32 MFMA ------------------
// 4 waves x 64 q-rows = 256-q tile. Q fragments in registers. K/V tiles
// double-buffered in LDS, staged before compute, ONE barrier per tile.
// No online max (scores bounded; exp2 domain, m=0). Softmax denominator via
// ones-row of V^T. P exchange via v_permlane32_swap_b32.
__global__ __launch_bounds__(256, 2) void k_attn(const bf16* __restrict__ Qg,
                                                 const bf16* __restrict__ Kg,
                                                 const bf16* __restrict__ Vg,
                                                 bf16* __restrict__ Oo) {
  __shared__ bf16 sK[2][3 * 64 * 32];   // 2 x 12 KB
  __shared__ bf16 sV[2][96 * 64];       // 2 x 12 KB
  const int t = threadIdx.x, wave = t >> 6, lane = t & 63;
  const int c = lane & 31, hi = lane >> 5;
  const int s = blockIdx.z, h = blockIdx.y, q0 = blockIdx.x * 256;
  const bf16* Qb = Qg + (size_t)(s * NH + h) * 3 * SEGL * 32;
  const bf16* Kb = Kg + (size_t)(s * NH + h) * 3 * SEGL * 32;
  const bf16* Vb = Vg + (size_t)(s * NH + h) * 96 * SEGL;

  // ---- Q fragments: direct global -> registers (constant across kv tiles) ----
  bf16x8 Qf[2][5];
#pragma unroll
  for (int sni = 0; sni < 2; sni++)
#pragma unroll
    for (int kk = 0; kk < 5; kk++) {
      int qr = q0 + wave * 64 + sni * 32 + c;
      Qf[sni][kk] = *(const bf16x8*)&Qb[(size_t)(kk >> 1) * (SEGL * 32) +
                                        (size_t)qr * 32 + ((kk & 1) * 2 + hi) * 8];
    }

  // ---- stage K,V tile 0 into buffer 0 ----
#pragma unroll
  for (int i = 0; i < 3; i++) {
    int ch = wave * 3 + i;
    int kk = ch >> 2;
    int r = (ch & 3) * 16 + (lane >> 2);
    int g = (lane & 3) ^ ((r >> 1) & 3);
    gload16(Kb + (size_t)kk * (SEGL * 32) + (size_t)r * 32 + g * 8,
            (char*)sK[0] + ch * 1024);
  }
#pragma unroll
  for (int i = 0; i < 3; i++) {
    int ch = wave * 3 + i;
    int r = ch * 8 + (lane >> 3);
    int g = (lane & 7) ^ (r & 7);
    gload16(Vb + (size_t)r * SEGL + g * 8, (char*)sV[0] + ch * 1024);
  }
  __syncthreads();

  f32x16 accO[3][2];
#pragma unroll
  for (int df = 0; df < 3; df++)
#pragma unroll
    for (int sni = 0; sni < 2; sni++)
#pragma unroll
      for (int r = 0; r < 16; r++) accO[df][sni][r] = 0.f;

  int cur = 0;
  for (int tile = 0; tile < 32; ++tile) {
    // ---- issue next-tile staging into the other buffer (overlaps compute) ----
    if (tile + 1 < 32) {
      int kv0 = (tile + 1) * 64;
#pragma unroll
      for (int i = 0; i < 3; i++) {
        int ch = wave * 3 + i;
        int kk = ch >> 2;
        int r = (ch & 3) * 16 + (lane >> 2);
        int g = (lane & 3) ^ ((r >> 1) & 3);
        gload16(Kb + (size_t)kk * (SEGL * 32) + (size_t)(kv0 + r) * 32 + g * 8,
                (char*)sK[cur ^ 1] + ch * 1024);
      }
#pragma unroll
      for (int i = 0; i < 3; i++) {
        int ch = wave * 3 + i;
        int r = ch * 8 + (lane >> 3);
        int g = (lane & 7) ^ (r & 7);
        gload16(Vb + (size_t)r * SEGL + kv0 + g * 8, (char*)sV[cur ^ 1] + ch * 1024);
      }
    }

    // ===== S^T = K · Q  (C: col = q (lane&31), rows = kv) =====
    f32x16 S[2][2];
#pragma unroll
    for (int smi = 0; smi < 2; smi++)
#pragma unroll
      for (int sni = 0; sni < 2; sni++)
#pragma unroll
        for (int r = 0; r < 16; r++) S[smi][sni][r] = 0.f;
    __builtin_amdgcn_s_setprio(1);
#pragma unroll
    for (int kk = 0; kk < 5; kk++) {
      bf16x8 Kf[2];
#pragma unroll
      for (int smi = 0; smi < 2; smi++) {
        int kr = smi * 32 + c;
        int g = (((kk & 1) * 2 + hi) ^ ((kr >> 1) & 3));
        Kf[smi] = *(const bf16x8*)&sK[cur][(kk >> 1) * 2048 + kr * 32 + g * 8];
      }
#pragma unroll
      for (int smi = 0; smi < 2; smi++)
#pragma unroll
        for (int sni = 0; sni < 2; sni++)
          S[smi][sni] = __builtin_amdgcn_mfma_f32_32x32x16_bf16(Kf[smi], Qf[sni][kk], S[smi][sni], 0, 0, 0);
    }
    __builtin_amdgcn_s_setprio(0);

    // ===== O^T += V^T · P^T  (P = exp2(S) folded into the pack; no max) =====
    __builtin_amdgcn_s_setprio(1);
#pragma unroll
    for (int kk = 0; kk < 4; kk++) {
      bf16x8 Vf[3];
#pragma unroll
      for (int df = 0; df < 3; df++) {
        int dr = df * 32 + c;
        int g = ((kk * 2 + hi) ^ (dr & 7));
        Vf[df] = *(const bf16x8*)&sV[cur][dr * 64 + g * 8];
      }
#pragma unroll
      for (int sni = 0; sni < 2; sni++) {
        const int smi = kk >> 1;
        const int base = (kk & 1) * 8;
        unsigned u0 = pk2(__builtin_amdgcn_exp2f(S[smi][sni][base + 0]),
                          __builtin_amdgcn_exp2f(S[smi][sni][base + 1]));
        unsigned u1 = pk2(__builtin_amdgcn_exp2f(S[smi][sni][base + 2]),
                          __builtin_amdgcn_exp2f(S[smi][sni][base + 3]));
        unsigned u2 = pk2(__builtin_amdgcn_exp2f(S[smi][sni][base + 4]),
                          __builtin_amdgcn_exp2f(S[smi][sni][base + 5]));
        unsigned u3 = pk2(__builtin_amdgcn_exp2f(S[smi][sni][base + 6]),
                          __builtin_amdgcn_exp2f(S[smi][sni][base + 7]));
        // [u0,u1|u2,u3] half-wave exchange: one permlane32_swap yields BOTH
        // output registers (lo keeps own low-ks, hi receives partner's).
        asm volatile("v_permlane32_swap_b32 %0, %1" : "+v"(u0), "+v"(u2));
        asm volatile("v_permlane32_swap_b32 %0, %1" : "+v"(u1), "+v"(u3));
        union { bf16x8 v; unsigned u[4]; } pb;
        pb.u[0] = u0; pb.u[1] = u1; pb.u[2] = u2; pb.u[3] = u3;
#pragma unroll
        for (int df = 0; df < 3; df++)
          accO[df][sni] = __builtin_amdgcn_mfma_f32_32x32x16_bf16(Vf[df], pb.v, accO[df][sni], 0, 0, 0);
      }
    }
    __builtin_amdgcn_s_setprio(0);

    // one barrier per tile: drains this thread's staging loads (vmcnt) too
    __syncthreads();
    cur ^= 1;
  }

  // ===== write O (token-major), 8 B packed stores =====
  // l = sum(P) sits in accO[2][sni][4] on hi=0 lanes (V^T ones-row at d=72;
  // hi=1's reg4 maps to zero-row d=76). own + partner = l on both halves.
#pragma unroll
  for (int sni = 0; sni < 2; sni++) {
    float lown = accO[2][sni][4];
    float lv = lown + __shfl_xor(lown, 32, 64);
    float inv = 1.f / lv;
    int token = s * SEGL + q0 + wave * 64 + sni * 32 + c;
#pragma unroll
    for (int df = 0; df < 3; df++)
#pragma unroll
      for (int rg = 0; rg < 4; rg++) {
        int d0 = df * 32 + rg * 8 + hi * 4;
        if (d0 < HD) {
          ushort4_t w;
          w[0] = __builtin_bit_cast(unsigned short, (bf16)(accO[df][sni][rg * 4 + 0] * inv));
          w[1] = __builtin_bit_cast(unsigned short, (bf16)(accO[df][sni][rg * 4 + 1] * inv));
          w[2] = __builtin_bit_cast(unsigned short, (bf16)(accO[df][sni][rg * 4 + 2] * inv));
          w[3] = __builtin_bit_cast(unsigned short, (bf16)(accO[df][sni][rg * 4 + 3] * inv));
          *(ushort4_t*)&Oo[(size_t)token * DIMM + h * HD + d0] = w;
        }
      }
  }
}

// -------------------------------------------------------------------------------
extern "C" void kernel_launch(void* const* d_in, const int* in_sizes, int n_in,
                              void* d_out, int out_size, void* d_ws, size_t ws_size,
                              hipStream_t stream) {
  (void)in_sizes; (void)n_in; (void)out_size; (void)ws_size;
  const float* hs     = (const float*)d_in[0];
  const float* cosp   = (const float*)d_in[1];
  const float* sinp   = (const float*)d_in[2];
  const float* w_qkv  = (const float*)d_in[4];
  const float* b_qkv  = (const float*)d_in[5];
  const float* w_proj = (const float*)d_in[6];
  const float* b_proj = (const float*)d_in[7];
  float* out = (float*)d_out;

  char* ws = (char*)d_ws;
  bf16* hsb    = (bf16*)(ws + 0);          // 18874368
  bf16* wqkvT  = (bf16*)(ws + 18874368);   //  7962624
  bf16* wprojT = (bf16*)(ws + 26836992);   //  2654208
  bf16* qkv    = (bf16*)(ws + 29491200);   // 56623104
  bf16* Qp     = (bf16*)(ws + 86114304);   // 25165824
  bf16* Kp     = (bf16*)(ws + 111280128);  // 25165824
  bf16* Vt     = (bf16*)(ws + 136445952);  // 25165824
  bf16* ao     = (bf16*)(ws + 161611776);  // 18874368

  k_cvt<<<4608, 256, 0, stream>>>(hs, hsb, 1179648);
  k_twt<<<dim3(54, 18), 256, 0, stream>>>(w_qkv, wqkvT, 1152, 3456);
  k_twt<<<dim3(18, 18), 256, 0, stream>>>(w_proj, wprojT, 1152, 1152);
  k_gemm256<<<864, 512, 0, stream>>>(hsb, wqkvT, b_qkv, qkv, 8192, 3456, 1152, 27);
  k_rope<<<8192, 256, 0, stream>>>(qkv, cosp, sinp, Qp, Kp);
  k_vrep<<<dim3(32, 16, 4), 256, 0, stream>>>(qkv, Vt);
  k_attn<<<dim3(8, 16, 4), 256, 0, stream>>>(Qp, Kp, Vt, ao);
  k_gemm<true><<<576, 256, 0, stream>>>(ao, wprojT, b_proj, (void*)out, 8192, 1152, 1152, 9);
}

// Round 5
// 292.295 us; speedup vs baseline: 1.8170x; 1.0838x over previous
//
#include <hip/hip_runtime.h>
#include <hip/hip_bf16.h>
#include <cstdint>
#include <cstddef>

typedef __bf16 bf16;
typedef __attribute__((ext_vector_type(8))) __bf16 bf16x8;
typedef __attribute__((ext_vector_type(4))) float f32x4;
typedef __attribute__((ext_vector_type(16))) float f32x16;
typedef __attribute__((ext_vector_type(4))) float floatx4;
typedef __attribute__((ext_vector_type(4))) unsigned short ushort4_t;

// Problem constants
#define NTOK 8192
#define DIMM 1152
#define NH   16
#define HD   72
#define SEGS 4
#define SEGL 2048

__device__ __forceinline__ void gload16(const void* gsrc, void* ldst) {
  __builtin_amdgcn_global_load_lds(
      (const __attribute__((address_space(1))) void*)gsrc,
      (__attribute__((address_space(3))) void*)ldst,
      16, 0, 0);
}

__device__ __forceinline__ unsigned pk2(float a, float b) {
  unsigned short x = __builtin_bit_cast(unsigned short, (bf16)a);
  unsigned short y = __builtin_bit_cast(unsigned short, (bf16)b);
  return (unsigned)x | ((unsigned)y << 16);
}

// ---------------- f32 -> bf16 elementwise convert (8 elems/thread) -------------
__global__ __launch_bounds__(256) void k_cvt(const float* __restrict__ src,
                                             bf16* __restrict__ dst, int n8) {
  int i = blockIdx.x * 256 + threadIdx.x;
  if (i >= n8) return;
  const floatx4* s = (const floatx4*)src + (size_t)i * 2;
  floatx4 a = s[0], b = s[1];
  bf16x8 o;
  o[0] = (bf16)a.x; o[1] = (bf16)a.y; o[2] = (bf16)a.z; o[3] = (bf16)a.w;
  o[4] = (bf16)b.x; o[5] = (bf16)b.y; o[6] = (bf16)b.z; o[7] = (bf16)b.w;
  *((bf16x8*)dst + i) = o;
}

// ------- transpose + convert: src[R][C] f32 -> dst[Cpad][R] bf16 (pad -> 0) ----
__global__ __launch_bounds__(256) void k_twt(const float* __restrict__ src,
                                             bf16* __restrict__ dst, int R, int C) {
  __shared__ bf16 tile[64][73];
  int bc = blockIdx.x * 64, br = blockIdx.y * 64;
  int t = threadIdx.x;
#pragma unroll
  for (int i = 0; i < 16; i++) {
    int idx = i * 256 + t;
    int r = idx >> 6, c = idx & 63;
    float v = (bc + c < C) ? src[(size_t)(br + r) * C + bc + c] : 0.f;
    tile[c][r] = (bf16)v;
  }
  __syncthreads();
#pragma unroll
  for (int i = 0; i < 16; i++) {
    int idx = i * 256 + t;
    int r = idx >> 6, c = idx & 63;
    dst[(size_t)(bc + r) * R + br + c] = tile[r][c];
  }
}

// ------------- bf16 GEMM 128x128 (proj): C = A * Bt^T + bias, XCD swizzle ------
// LDS tiles XOR-swizzled (group^row&7) via pre-swizzled global source.
template <bool OUT_F32>
__global__ __launch_bounds__(256) void k_gemm(const bf16* __restrict__ A,
                                              const bf16* __restrict__ Bt,
                                              const float* __restrict__ bias,
                                              void* __restrict__ Cout,
                                              int M, int N, int K, int gx) {
  __shared__ bf16 sA[128 * 64];
  __shared__ bf16 sB[128 * 64];
  const int t = threadIdx.x, wave = t >> 6, lane = t & 63;
  const int lr = lane & 15, lg = lane >> 4;
  const int nwg = gridDim.x, bid = blockIdx.x;
  const int swz = (bid & 7) * (nwg >> 3) + (bid >> 3);
  const int bx = swz % gx, by = swz / gx;
  const int m0 = by * 128, n0 = bx * 128;
  const int wm = (wave >> 1) * 64, wn = (wave & 1) * 64;
  f32x4 acc[4][4];
#pragma unroll
  for (int i = 0; i < 4; i++)
#pragma unroll
    for (int j = 0; j < 4; j++)
#pragma unroll
      for (int q = 0; q < 4; q++) acc[i][j][q] = 0.f;

  const bf16* Ab = A + (size_t)m0 * K;
  const bf16* Bb = Bt + (size_t)n0 * K;
  const int rst = (threadIdx.x >> 3);          // row within 32-row chunk piece
  const int gsw = ((t & 7) ^ ((t >> 3) & 7)) * 8;  // pre-swizzled source group

  for (int k0 = 0; k0 < K; k0 += 64) {
#pragma unroll
    for (int it = 0; it < 4; ++it) {
      int r = it * 32 + rst;
      int gs = ((t & 7) ^ (r & 7)) * 8;
      gload16(Ab + (size_t)r * K + k0 + gs, (char*)sA + it * 4096 + wave * 1024);
      gload16(Bb + (size_t)r * K + k0 + gs, (char*)sB + it * 4096 + wave * 1024);
    }
    __syncthreads();
#pragma unroll
    for (int kk = 0; kk < 2; ++kk) {
      bf16x8 av[4], bv[4];
#pragma unroll
      for (int mi = 0; mi < 4; ++mi)
        av[mi] = *(const bf16x8*)&sA[(wm + mi * 16 + lr) * 64 + (((kk * 4 + lg) ^ (lr & 7)) * 8)];
#pragma unroll
      for (int ni = 0; ni < 4; ++ni)
        bv[ni] = *(const bf16x8*)&sB[(wn + ni * 16 + lr) * 64 + (((kk * 4 + lg) ^ (lr & 7)) * 8)];
#pragma unroll
      for (int mi = 0; mi < 4; ++mi)
#pragma unroll
        for (int ni = 0; ni < 4; ++ni)
          acc[mi][ni] = __builtin_amdgcn_mfma_f32_16x16x32_bf16(av[mi], bv[ni], acc[mi][ni], 0, 0, 0);
    }
    __syncthreads();
  }
#pragma unroll
  for (int mi = 0; mi < 4; ++mi)
#pragma unroll
    for (int ni = 0; ni < 4; ++ni) {
      int col = n0 + wn + ni * 16 + lr;
      float bc_ = bias[col];
#pragma unroll
      for (int j = 0; j < 4; j++) {
        int row = m0 + wm + mi * 16 + lg * 4 + j;
        float v = acc[mi][ni][j] + bc_;
        if (OUT_F32)
          ((float*)Cout)[(size_t)row * N + col] = v;
        else
          ((bf16*)Cout)[(size_t)row * N + col] = (bf16)v;
      }
    }
}

// ---- bf16 GEMM 256x256 (QKV): counted-vmcnt phase pipeline (T2+T3+T4+T5) ------
// 8 waves (2M x 4N), per-wave 128x64 output. K processed in 64-tiles split into
// two 32-wide K-halves; LDS [2dbuf][2khalf][256][32] per operand (128 KB).
// Per phase: vmcnt(4) -> s_barrier -> 12 swizzled ds_read_b128 -> stage 4
// global_load_lds for tile t+1 -> setprio(1) 32 MFMA setprio(0).
// vmcnt never drains to 0 in the main loop (except the very last phase).
// Cols are padded to a multiple of 256; stores/bias guarded to col < Nreal.
template <bool OUT_F32>
__global__ __launch_bounds__(512, 2) void k_gemm8(const bf16* __restrict__ A,
                                                  const bf16* __restrict__ Bt,
                                                  const float* __restrict__ bias,
                                                  void* __restrict__ Cout,
                                                  int M, int Nreal, int K, int gx) {
  __shared__ bf16 sA[2][2][256 * 32];
  __shared__ bf16 sB[2][2][256 * 32];
  const int t = threadIdx.x, wave = t >> 6, lane = t & 63;
  const int lr = lane & 15, lg = lane >> 4;
  const int nwg = gridDim.x, bid = blockIdx.x;
  const int swz = (bid & 7) * (nwg >> 3) + (bid >> 3);
  const int bx = swz % gx, by = swz / gx;
  const int m0 = by * 256, n0 = bx * 256;
  const int wr = wave >> 2;                 // 0..1 : 128-row half
  const int wn = (wave & 3) * 64;           // 0..3 : 64-col strip
  const int NT = K >> 6;

  f32x4 acc[8][4];
#pragma unroll
  for (int i = 0; i < 8; i++)
#pragma unroll
    for (int j = 0; j < 4; j++)
#pragma unroll
      for (int q = 0; q < 4; q++) acc[i][j][q] = 0.f;

  const bf16* Ab = A + (size_t)m0 * K;
  const bf16* Bb = Bt + (size_t)n0 * K;
  // staging: thread covers physical row rw = u*128 + (t>>2), group t&3 of a
  // [256][32] slot; source pre-swizzled: logical group = (t&3) ^ ((rw>>1)&3).
  const int glsw = ((t & 3) ^ ((t >> 3) & 3)) * 8;
  const bf16* Asrc0 = Ab + (size_t)(t >> 2) * K + glsw;
  const bf16* Asrc1 = Ab + (size_t)((t >> 2) + 128) * K + glsw;
  const bf16* Bsrc0 = Bb + (size_t)(t >> 2) * K + glsw;
  const bf16* Bsrc1 = Bb + (size_t)((t >> 2) + 128) * K + glsw;
  // fragment read offsets (elements) within a [256][32] slot, XOR-swizzled
  const int swz4 = (lr >> 1) & 3;
  const int aoff = (wr * 128 + lr) * 32 + ((lg ^ swz4) * 8);   // + mi*512
  const int boff = (wn + lr) * 32 + ((lg ^ swz4) * 8);          // + ni*512

  // ---- prologue: stage tile 0 (both K-halves) ----
#pragma unroll
  for (int kh = 0; kh < 2; ++kh) {
    const int k0 = kh * 32;
    char* dA = (char*)&sA[0][kh][0] + wave * 1024;
    char* dB = (char*)&sB[0][kh][0] + wave * 1024;
    gload16(Asrc0 + k0, dA);
    gload16(Bsrc0 + k0, dB);
    gload16(Asrc1 + k0, dA + 8192);
    gload16(Bsrc1 + k0, dB + 8192);
  }

  for (int kt = 0; kt < NT; ++kt) {
    const int buf = kt & 1;
    const bool more = (kt + 1 < NT);
#pragma unroll
    for (int kh = 0; kh < 2; ++kh) {
      if (!more && kh == 1) {
        asm volatile("s_waitcnt vmcnt(0)" ::: "memory");
      } else {
        asm volatile("s_waitcnt vmcnt(4)" ::: "memory");
      }
      __builtin_amdgcn_s_barrier();
      __builtin_amdgcn_sched_barrier(0);
      const bf16* As = &sA[buf][kh][0];
      const bf16* Bs = &sB[buf][kh][0];
      bf16x8 av[8], bv[4];
#pragma unroll
      for (int mi = 0; mi < 8; mi++)
        av[mi] = *(const bf16x8*)&As[aoff + mi * 512];
#pragma unroll
      for (int ni = 0; ni < 4; ni++)
        bv[ni] = *(const bf16x8*)&Bs[boff + ni * 512];
      if (more) {
        const int k0 = (kt + 1) * 64 + kh * 32;
        char* dA = (char*)&sA[buf ^ 1][kh][0] + wave * 1024;
        char* dB = (char*)&sB[buf ^ 1][kh][0] + wave * 1024;
        gload16(Asrc0 + k0, dA);
        gload16(Bsrc0 + k0, dB);
        gload16(Asrc1 + k0, dA + 8192);
        gload16(Bsrc1 + k0, dB + 8192);
      }
      __builtin_amdgcn_s_setprio(1);
#pragma unroll
      for (int mi = 0; mi < 8; mi++)
#pragma unroll
        for (int ni = 0; ni < 4; ni++)
          acc[mi][ni] = __builtin_amdgcn_mfma_f32_16x16x32_bf16(av[mi], bv[ni], acc[mi][ni], 0, 0, 0);
      __builtin_amdgcn_s_setprio(0);
    }
  }

  // ---- epilogue: guarded store (cols < Nreal), bias add ----
#pragma unroll
  for (int mi = 0; mi < 8; ++mi)
#pragma unroll
    for (int ni = 0; ni < 4; ++ni) {
      int col = n0 + wn + ni * 16 + lr;
      if (col < Nreal) {
        float bc_ = bias[col];
#pragma unroll
        for (int j = 0; j < 4; j++) {
          int row = m0 + wr * 128 + mi * 16 + lg * 4 + j;
          float v = acc[mi][ni][j] + bc_;
          if (OUT_F32)
            ((float*)Cout)[(size_t)row * Nreal + col] = v;
          else
            ((bf16*)Cout)[(size_t)row * Nreal + col] = (bf16)v;
        }
      }
    }
}

// ---------------- RoPE + repack Q,K: qkv[n][3456] -> Qp/Kp[s][h][3][2048][32] --
// Q is pre-scaled by log2(e)/sqrt(72) so attention works in exp2 domain.
__global__ __launch_bounds__(256) void k_rope(const bf16* __restrict__ qkv,
                                              const float* __restrict__ cs,
                                              const float* __restrict__ sn,
                                              bf16* __restrict__ Qp,
                                              bf16* __restrict__ Kp) {
  int n = blockIdx.x;
  int s = n >> 11, l = n & 2047;
  const bf16* row = qkv + (size_t)n * (3 * DIMM);
  const float* cr = cs + (size_t)n * HD;
  const float* sr = sn + (size_t)n * HD;
  const float QS = 0.17002323f;  // log2(e)/sqrt(72)
  for (int e = threadIdx.x; e < 3072; e += 256) {
    int which = e / 1536;             // 0=q, 1=k
    int r = e - which * 1536;
    int h = r / 96;
    int d = r - h * 96;
    float v = 0.f;
    if (d < HD) {
      int base = which * DIMM + h * HD;
      float x = (float)row[base + d];
      float o = (d < 36) ? -(float)row[base + d + 36] : (float)row[base + d - 36];
      v = x * cr[d] + o * sr[d];
      if (which == 0) v *= QS;
    }
    bf16* dst = which ? Kp : Qp;
    dst[(((size_t)(s * NH + h) * 3 + (d >> 5)) * SEGL + l) * 32 + (d & 31)] = (bf16)v;
  }
}

// ---------------- V repack (transpose): qkv v-part -> Vt[s][h][96][2048] -------
// Row HD (=72) is set to 1.0: the PV MFMA then accumulates the softmax
// denominator l = sum(P) for free into the d=72 output row.
__global__ __launch_bounds__(256) void k_vrep(const bf16* __restrict__ qkv,
                                              bf16* __restrict__ Vt) {
  int s = blockIdx.z, h = blockIdx.y, l0 = blockIdx.x * 64;
  __shared__ bf16 tl[64][73];
  int t = threadIdx.x;
  for (int idx = t; idx < 64 * HD; idx += 256) {
    int l = idx / HD, d = idx - l * HD;
    tl[l][d] = qkv[(size_t)(s * SEGL + l0 + l) * (3 * DIMM) + 2 * DIMM + h * HD + d];
  }
  __syncthreads();
  for (int idx = t; idx < 96 * 64; idx += 256) {
    int d = idx >> 6, l = idx & 63;
    bf16 v = (d < HD) ? tl[l][d] : ((d == HD) ? (bf16)1.f : (bf16)0.f);
    Vt[((size_t)(s * NH + h) * 96 + d) * SEGL + l0 + l] = v;
  }
}

// ---------------- flash attention, swapped-operand 32x32 MFMA ------------------
__global__ __launch_bounds__(256, 2) void k_attn(const bf16* __restrict__ Qg,
                                                 const bf16* __restrict__ Kg,
                                                 const bf16* __restrict__ Vg,
                                                 bf16* __restrict__ Oo) {
  __shared__ bf16 sK[2][3 * 64 * 32];   // 2 x 12 KB
  __shared__ bf16 sV[2][96 * 64];       // 2 x 12 KB
  const int t = threadIdx.x, wave = t >> 6, lane = t & 63;
  const int c = lane & 31, hi = lane >> 5;
  const int s = blockIdx.z, h = blockIdx.y, q0 = blockIdx.x * 256;
  const bf16* Qb = Qg + (size_t)(s * NH + h) * 3 * SEGL * 32;
  const bf16* Kb = Kg + (size_t)(s * NH + h) * 3 * SEGL * 32;
  const bf16* Vb = Vg + (size_t)(s * NH + h) * 96 * SEGL;

  // ---- Q fragments: direct global -> registers (constant across kv tiles) ----
  bf16x8 Qf[2][5];
#pragma unroll
  for (int sni = 0; sni < 2; sni++)
#pragma unroll
    for (int kk = 0; kk < 5; kk++) {
      int qr = q0 + wave * 64 + sni * 32 + c;
      Qf[sni][kk] = *(const bf16x8*)&Qb[(size_t)(kk >> 1) * (SEGL * 32) +
                                        (size_t)qr * 32 + ((kk & 1) * 2 + hi) * 8];
    }

  // ---- stage K,V tile 0 into buffer 0 ----
#pragma unroll
  for (int i = 0; i < 3; i++) {
    int ch = wave * 3 + i;
    int kk = ch >> 2;
    int r = (ch & 3) * 16 + (lane >> 2);
    int g = (lane & 3) ^ ((r >> 1) & 3);
    gload16(Kb + (size_t)kk * (SEGL * 32) + (size_t)r * 32 + g * 8,
            (char*)sK[0] + ch * 1024);
  }
#pragma unroll
  for (int i = 0; i < 3; i++) {
    int ch = wave * 3 + i;
    int r = ch * 8 + (lane >> 3);
    int g = (lane & 7) ^ (r & 7);
    gload16(Vb + (size_t)r * SEGL + g * 8, (char*)sV[0] + ch * 1024);
  }
  __syncthreads();

  f32x16 accO[3][2];
#pragma unroll
  for (int df = 0; df < 3; df++)
#pragma unroll
    for (int sni = 0; sni < 2; sni++)
#pragma unroll
      for (int r = 0; r < 16; r++) accO[df][sni][r] = 0.f;

  int cur = 0;
  for (int tile = 0; tile < 32; ++tile) {
    // ---- issue next-tile staging into the other buffer (overlaps compute) ----
    if (tile + 1 < 32) {
      int kv0 = (tile + 1) * 64;
#pragma unroll
      for (int i = 0; i < 3; i++) {
        int ch = wave * 3 + i;
        int kk = ch >> 2;
        int r = (ch & 3) * 16 + (lane >> 2);
        int g = (lane & 3) ^ ((r >> 1) & 3);
        gload16(Kb + (size_t)kk * (SEGL * 32) + (size_t)(kv0 + r) * 32 + g * 8,
                (char*)sK[cur ^ 1] + ch * 1024);
      }
#pragma unroll
      for (int i = 0; i < 3; i++) {
        int ch = wave * 3 + i;
        int r = ch * 8 + (lane >> 3);
        int g = (lane & 7) ^ (r & 7);
        gload16(Vb + (size_t)r * SEGL + kv0 + g * 8, (char*)sV[cur ^ 1] + ch * 1024);
      }
    }

    // ===== S^T = K · Q  (C: col = q (lane&31), rows = kv) =====
    f32x16 S[2][2];
#pragma unroll
    for (int smi = 0; smi < 2; smi++)
#pragma unroll
      for (int sni = 0; sni < 2; sni++)
#pragma unroll
        for (int r = 0; r < 16; r++) S[smi][sni][r] = 0.f;
    __builtin_amdgcn_s_setprio(1);
#pragma unroll
    for (int kk = 0; kk < 5; kk++) {
      bf16x8 Kf[2];
#pragma unroll
      for (int smi = 0; smi < 2; smi++) {
        int kr = smi * 32 + c;
        int g = (((kk & 1) * 2 + hi) ^ ((kr >> 1) & 3));
        Kf[smi] = *(const bf16x8*)&sK[cur][(kk >> 1) * 2048 + kr * 32 + g * 8];
      }
#pragma unroll
      for (int smi = 0; smi < 2; smi++)
#pragma unroll
        for (int sni = 0; sni < 2; sni++)
          S[smi][sni] = __builtin_amdgcn_mfma_f32_32x32x16_bf16(Kf[smi], Qf[sni][kk], S[smi][sni], 0, 0, 0);
    }
    __builtin_amdgcn_s_setprio(0);

    // ===== O^T += V^T · P^T  (P = exp2(S) folded into the pack; no max) =====
    __builtin_amdgcn_s_setprio(1);
#pragma unroll
    for (int kk = 0; kk < 4; kk++) {
      bf16x8 Vf[3];
#pragma unroll
      for (int df = 0; df < 3; df++) {
        int dr = df * 32 + c;
        int g = ((kk * 2 + hi) ^ (dr & 7));
        Vf[df] = *(const bf16x8*)&sV[cur][dr * 64 + g * 8];
      }
#pragma unroll
      for (int sni = 0; sni < 2; sni++) {
        const int smi = kk >> 1;
        const int base = (kk & 1) * 8;
        unsigned u0 = pk2(__builtin_amdgcn_exp2f(S[smi][sni][base + 0]),
                          __builtin_amdgcn_exp2f(S[smi][sni][base + 1]));
        unsigned u1 = pk2(__builtin_amdgcn_exp2f(S[smi][sni][base + 2]),
                          __builtin_amdgcn_exp2f(S[smi][sni][base + 3]));
        unsigned u2 = pk2(__builtin_amdgcn_exp2f(S[smi][sni][base + 4]),
                          __builtin_amdgcn_exp2f(S[smi][sni][base + 5]));
        unsigned u3 = pk2(__builtin_amdgcn_exp2f(S[smi][sni][base + 6]),
                          __builtin_amdgcn_exp2f(S[smi][sni][base + 7]));
        asm volatile("v_permlane32_swap_b32 %0, %1" : "+v"(u0), "+v"(u2));
        asm volatile("v_permlane32_swap_b32 %0, %1" : "+v"(u1), "+v"(u3));
        union { bf16x8 v; unsigned u[4]; } pb;
        pb.u[0] = u0; pb.u[1] = u1; pb.u[2] = u2; pb.u[3] = u3;
#pragma unroll
        for (int df = 0; df < 3; df++)
          accO[df][sni] = __builtin_amdgcn_mfma_f32_32x32x16_bf16(Vf[df], pb.v, accO[df][sni], 0, 0, 0);
      }
    }
    __builtin_amdgcn_s_setprio(0);

    __syncthreads();
    cur ^= 1;
  }

  // ===== write O (token-major), 8 B packed stores =====
#pragma unroll
  for (int sni = 0; sni < 2; sni++) {
    float lown = accO[2][sni][4];
    float lv = lown + __shfl_xor(lown, 32, 64);
    float inv = 1.f / lv;
    int token = s * SEGL + q0 + wave * 64 + sni * 32 + c;
#pragma unroll
    for (int df = 0; df < 3; df++)
#pragma unroll
      for (int rg = 0; rg < 4; rg++) {
        int d0 = df * 32 + rg * 8 + hi * 4;
        if (d0 < HD) {
          ushort4_t w;
          w[0] = __builtin_bit_cast(unsigned short, (bf16)(accO[df][sni][rg * 4 + 0] * inv));
          w[1] = __builtin_bit_cast(unsigned short, (bf16)(accO[df][sni][rg * 4 + 1] * inv));
          w[2] = __builtin_bit_cast(unsigned short, (bf16)(accO[df][sni][rg * 4 + 2] * inv));
          w[3] = __builtin_bit_cast(unsigned short, (bf16)(accO[df][sni][rg * 4 + 3] * inv));
          *(ushort4_t*)&Oo[(size_t)token * DIMM + h * HD + d0] = w;
        }
      }
  }
}

// -------------------------------------------------------------------------------
extern "C" void kernel_launch(void* const* d_in, const int* in_sizes, int n_in,
                              void* d_out, int out_size, void* d_ws, size_t ws_size,
                              hipStream_t stream) {
  (void)in_sizes; (void)n_in; (void)out_size; (void)ws_size;
  const float* hs     = (const float*)d_in[0];
  const float* cosp   = (const float*)d_in[1];
  const float* sinp   = (const float*)d_in[2];
  const float* w_qkv  = (const float*)d_in[4];
  const float* b_qkv  = (const float*)d_in[5];
  const float* w_proj = (const float*)d_in[6];
  const float* b_proj = (const float*)d_in[7];
  float* out = (float*)d_out;

  char* ws = (char*)d_ws;
  bf16* hsb    = (bf16*)(ws + 0);          // 18874368
  bf16* wprojT = (bf16*)(ws + 26836992);   //  2654208
  bf16* qkv    = (bf16*)(ws + 29491200);   // 56623104
  bf16* Qp     = (bf16*)(ws + 86114304);   // 25165824
  bf16* Kp     = (bf16*)(ws + 111280128);  // 25165824
  bf16* Vt     = (bf16*)(ws + 136445952);  // 25165824
  bf16* ao     = (bf16*)(ws + 161611776);  // 18874368
  // wqkvT (padded to 3584 rows, 8257536 B) aliases the ao region: wqkvT's
  // lifetime (k_twt -> k_gemm8) ends before attn writes ao.
  bf16* wqkvT  = (bf16*)(ws + 161611776);

  k_cvt<<<4608, 256, 0, stream>>>(hs, hsb, 1179648);
  k_twt<<<dim3(56, 18), 256, 0, stream>>>(w_qkv, wqkvT, 1152, 3456);   // 3584-pad
  k_twt<<<dim3(18, 18), 256, 0, stream>>>(w_proj, wprojT, 1152, 1152);
  k_gemm8<false><<<448, 512, 0, stream>>>(hsb, wqkvT, b_qkv, (void*)qkv, 8192, 3456, 1152, 14);
  k_rope<<<8192, 256, 0, stream>>>(qkv, cosp, sinp, Qp, Kp);
  k_vrep<<<dim3(32, 16, 4), 256, 0, stream>>>(qkv, Vt);
  k_attn<<<dim3(8, 16, 4), 256, 0, stream>>>(Qp, Kp, Vt, ao);
  k_gemm<true><<<576, 256, 0, stream>>>(ao, wprojT, b_proj, (void*)out, 8192, 1152, 1152, 9);
}